// Round 8
// baseline (667.601 us; speedup 1.0000x reference)
//
#include <hip/hip_runtime.h>
#include <math.h>

// Problem constants (LFM2AudioDetokenizer)
#define B_    2
#define T_    256
#define S_    1536      // T*6
#define D_    512
#define H_    8
#define DH_   64
#define FF_   2048
#define V_    2048
#define NL_   4
#define NFFT_ 1280
#define HOP_  320
#define WIN_  1280
#define NBIN_ 641
#define NC_   1282
#define NPADL 1344      // 1282 padded to mult of 64 (final-linear col tiles)
#define PAD_  480
#define OUTL_ 491520    // (S-1)*HOP + WIN - 2*PAD
#define SWIN_ 30
#define ROW_  (B_ * S_) // 3072
// Half-spectrum ISTFT (cos/sin symmetry) dims
#define NH_   641       // output cols n = 0..640
#define KH_   704       // K = 641 padded to mult of 64
#define NHP2_ 768       // B rows padded to mult of 128 (wide tiles)

#define TWO_PI_OVER_N 0.004908738521234052f   // 2*pi/1280

typedef unsigned short ushort_t;
typedef __attribute__((ext_vector_type(8))) short short8;
typedef __attribute__((ext_vector_type(8))) unsigned short ushort8_t;
typedef __attribute__((ext_vector_type(4))) float f32x4;

__device__ __forceinline__ ushort_t f2bf(float x) {
    unsigned int u = __builtin_bit_cast(unsigned int, x);
    u = (u + 0x7fffu + ((u >> 16) & 1u)) >> 16;
    return (ushort_t)u;
}
__device__ __forceinline__ float bf2f(ushort_t h) {
    unsigned int u = ((unsigned int)h) << 16;
    return __builtin_bit_cast(float, u);
}

#define GLL16(gp, sp) \
    __builtin_amdgcn_global_load_lds((const __attribute__((address_space(1))) void*)(gp), \
                                     (__attribute__((address_space(3))) void*)(sp), 16, 0, 0)

// BK=64 swizzled LDS row: 128B = 8 x 16B slots; slot = (jg + (r>>1)) & 7.
__device__ __forceinline__ int fragoff(int r, int kg) {
    return r * 128 + (((kg + (r >> 1)) & 7) * 16);
}

// ---------------------------------------------------------------------------
__global__ __launch_bounds__(256) void k_embed(const int* __restrict__ codes,
                                               const float* __restrict__ emb,
                                               float* __restrict__ X)
{
    int idx = blockIdx.x * 256 + threadIdx.x;
    int d  = idx & (D_ - 1);
    int bt = idx >> 9;
    int t  = bt & (T_ - 1);
    int b  = bt >> 8;
    float s = 0.f;
#pragma unroll
    for (int cb = 0; cb < 8; ++cb) {
        int code = codes[(b * 8 + cb) * T_ + t];
        s += emb[(size_t)(cb * V_ + code) * D_ + d];
    }
    s *= 0.125f;
    float* xp = X + (size_t)(b * S_ + t * 6) * D_ + d;
#pragma unroll
    for (int r = 0; r < 6; ++r) xp[(size_t)r * D_] = s;
}

// ---------------------------------------------------------------------------
// RMSNorm over D=512 -> bf16. Optional: fuse partial-sum X += P0+P1 (split-K
// down-proj) with X write-back; optional lo output for split consumers.
__global__ __launch_bounds__(256) void k_rmsnorm(float* __restrict__ X,
                                                 const float* __restrict__ P0,
                                                 const float* __restrict__ P1,
                                                 const float* __restrict__ w,
                                                 ushort_t* __restrict__ Hh,
                                                 ushort_t* __restrict__ Hl)
{
    int row = blockIdx.x;
    int tid = threadIdx.x;
    float* x = X + (size_t)row * D_;
    float v0 = x[tid], v1 = x[tid + 256];
    if (P0) {
        size_t b = (size_t)row * D_;
        v0 += P0[b + tid] + P1[b + tid];
        v1 += P0[b + tid + 256] + P1[b + tid + 256];
        x[tid] = v0; x[tid + 256] = v1;
    }
    float ss = v0 * v0 + v1 * v1;
#pragma unroll
    for (int m = 1; m < 64; m <<= 1) ss += __shfl_xor(ss, m);
    __shared__ float red[4];
    if ((tid & 63) == 0) red[tid >> 6] = ss;
    __syncthreads();
    float tot = red[0] + red[1] + red[2] + red[3];
    float sc = rsqrtf(tot * (1.f / (float)D_) + 1e-5f);
    float y0 = v0 * sc * w[tid];
    float y1 = v1 * sc * w[tid + 256];
    ushort_t h0 = f2bf(y0), h1 = f2bf(y1);
    Hh[(size_t)row * D_ + tid]       = h0;
    Hh[(size_t)row * D_ + tid + 256] = h1;
    if (Hl) {
        Hl[(size_t)row * D_ + tid]       = f2bf(y0 - bf2f(h0));
        Hl[(size_t)row * D_ + tid + 256] = f2bf(y1 - bf2f(h1));
    }
}

// ---------------------------------------------------------------------------
// Transpose-cast f32 [K,N] -> bf16 [Npad,K] (rows >= N zero-filled).
__global__ __launch_bounds__(256) void k_castT(const float* __restrict__ src,
                                               ushort_t* __restrict__ dh,
                                               ushort_t* __restrict__ dl,
                                               int K, int N,
                                               long srcBatchStride, long dstBatchStride)
{
    src += (size_t)blockIdx.z * srcBatchStride;
    dh  += (size_t)blockIdx.z * dstBatchStride;
    if (dl) dl += (size_t)blockIdx.z * dstBatchStride;
    __shared__ float t[32][33];
    int n0 = blockIdx.x * 32, k0 = blockIdx.y * 32;
    int tx = threadIdx.x & 31, ty = threadIdx.x >> 5;   // 32 x 8
#pragma unroll
    for (int i = 0; i < 4; ++i) {
        int k = k0 + ty + 8 * i, n = n0 + tx;
        t[ty + 8 * i][tx] = (n < N) ? src[(size_t)k * N + n] : 0.f;
    }
    __syncthreads();
#pragma unroll
    for (int i = 0; i < 4; ++i) {
        int n = n0 + ty + 8 * i;
        float v = t[tx][ty + 8 * i];
        ushort_t h = f2bf(v);
        dh[(size_t)n * K + k0 + tx] = h;
        if (dl) dl[(size_t)n * K + k0 + tx] = f2bf(v - bf2f(h));
    }
}

// ---------------------------------------------------------------------------
// 64x64-tile MFMA GEMM, BK=64, XCD swizzle. SPLIT: bf16x2. Kloop may be a
// slice of Kstride (split-K via blockIdx.z + az/bz/cz pointer strides).
template<bool SPLIT, bool CBF16, bool HASRES, bool HASBIAS>
__global__ __launch_bounds__(256) void gemm_mfma(
    const ushort_t* __restrict__ Ah, const ushort_t* __restrict__ Al,
    const ushort_t* __restrict__ Bh, const ushort_t* __restrict__ Bl,
    const float* __restrict__ Res, const float* __restrict__ bias,
    float* __restrict__ Cf, ushort_t* __restrict__ Cb,
    int Kloop, int Kstride, int Nstore, size_t az, size_t bz, size_t cz)
{
    const size_t zo = blockIdx.z;
    Ah += zo * az; Bh += zo * bz;
    if (SPLIT) { Al += zo * az; Bl += zo * bz; }
    if (CBF16) Cb += zo * cz; else Cf += zo * cz;

    const int f  = blockIdx.y * gridDim.x + blockIdx.x;
    const int tx = f / gridDim.y;
    const int ty = f - tx * gridDim.y;

    __shared__ __align__(16) ushort_t lds[SPLIT ? 16384 : 8192];
    ushort_t* AsH = lds;            // 64 rows x 128B = 8KB
    ushort_t* BsH = lds + 4096;

    const int tid  = threadIdx.x;
    const int wave = tid >> 6, lane = tid & 63;
    const int row0 = ty * 64;
    const int col0 = tx * 64;
    const int wr = (wave >> 1) * 32, wc = (wave & 1) * 32;

    const int sr0 = tid >> 3, js = tid & 7;
    const int jg  = (js - (sr0 >> 1)) & 7;    // same for +32 rows (16 ≡ 0 mod 8)
    const size_t aSrc0 = (size_t)(row0 + sr0) * Kstride + jg * 8;
    const size_t aSrc1 = (size_t)(row0 + 32 + sr0) * Kstride + jg * 8;
    const size_t bSrc0 = (size_t)(col0 + sr0) * Kstride + jg * 8;
    const size_t bSrc1 = (size_t)(col0 + 32 + sr0) * Kstride + jg * 8;
    const int d0 = tid * 16, d1 = d0 + 4096;

    const int kg = lane >> 4;
    const int lr = lane & 15;
    const int offA0 = fragoff(wr + lr, kg);
    const int offA1 = fragoff(wr + 16 + lr, kg);
    const int offB0 = fragoff(wc + lr, kg);
    const int offB1 = fragoff(wc + 16 + lr, kg);

    f32x4 acc00 = {0.f,0.f,0.f,0.f}, acc01 = acc00, acc10 = acc00, acc11 = acc00;

    for (int k0 = 0; k0 < Kloop; k0 += 64) {
        GLL16(Ah + aSrc0 + k0, (char*)AsH + d0);
        GLL16(Ah + aSrc1 + k0, (char*)AsH + d1);
        GLL16(Bh + bSrc0 + k0, (char*)BsH + d0);
        GLL16(Bh + bSrc1 + k0, (char*)BsH + d1);
        if constexpr (SPLIT) {
            GLL16(Al + aSrc0 + k0, (char*)(lds + 8192)  + d0);
            GLL16(Al + aSrc1 + k0, (char*)(lds + 8192)  + d1);
            GLL16(Bl + bSrc0 + k0, (char*)(lds + 12288) + d0);
            GLL16(Bl + bSrc1 + k0, (char*)(lds + 12288) + d1);
        }
        __syncthreads();
#pragma unroll
        for (int h = 0; h < 2; ++h) {
            const int hx = h * 64;
            short8 a0 = *(const short8*)((const char*)AsH + (offA0 ^ hx));
            short8 a1 = *(const short8*)((const char*)AsH + (offA1 ^ hx));
            short8 b0 = *(const short8*)((const char*)BsH + (offB0 ^ hx));
            short8 b1 = *(const short8*)((const char*)BsH + (offB1 ^ hx));
            acc00 = __builtin_amdgcn_mfma_f32_16x16x32_bf16(a0, b0, acc00, 0, 0, 0);
            acc01 = __builtin_amdgcn_mfma_f32_16x16x32_bf16(a0, b1, acc01, 0, 0, 0);
            acc10 = __builtin_amdgcn_mfma_f32_16x16x32_bf16(a1, b0, acc10, 0, 0, 0);
            acc11 = __builtin_amdgcn_mfma_f32_16x16x32_bf16(a1, b1, acc11, 0, 0, 0);
            if constexpr (SPLIT) {
                short8 al0 = *(const short8*)((const char*)(lds + 8192)  + (offA0 ^ hx));
                short8 al1 = *(const short8*)((const char*)(lds + 8192)  + (offA1 ^ hx));
                short8 bl0 = *(const short8*)((const char*)(lds + 12288) + (offB0 ^ hx));
                short8 bl1 = *(const short8*)((const char*)(lds + 12288) + (offB1 ^ hx));
                acc00 = __builtin_amdgcn_mfma_f32_16x16x32_bf16(a0, bl0, acc00, 0, 0, 0);
                acc00 = __builtin_amdgcn_mfma_f32_16x16x32_bf16(al0, b0, acc00, 0, 0, 0);
                acc01 = __builtin_amdgcn_mfma_f32_16x16x32_bf16(a0, bl1, acc01, 0, 0, 0);
                acc01 = __builtin_amdgcn_mfma_f32_16x16x32_bf16(al0, b1, acc01, 0, 0, 0);
                acc10 = __builtin_amdgcn_mfma_f32_16x16x32_bf16(a1, bl0, acc10, 0, 0, 0);
                acc10 = __builtin_amdgcn_mfma_f32_16x16x32_bf16(al1, b0, acc10, 0, 0, 0);
                acc11 = __builtin_amdgcn_mfma_f32_16x16x32_bf16(a1, bl1, acc11, 0, 0, 0);
                acc11 = __builtin_amdgcn_mfma_f32_16x16x32_bf16(al1, b1, acc11, 0, 0, 0);
            }
        }
        __syncthreads();
    }

    const int crow = row0 + wr + (lane >> 4) * 4;
    const int ccol = col0 + wc + lr;
#pragma unroll
    for (int i = 0; i < 2; ++i) {
#pragma unroll
        for (int j = 0; j < 2; ++j) {
            const f32x4 a = (i == 0) ? (j == 0 ? acc00 : acc01) : (j == 0 ? acc10 : acc11);
            int c = ccol + j * 16;
            if (c >= Nstore) continue;
            float bi = HASBIAS ? bias[c] : 0.f;
#pragma unroll
            for (int r = 0; r < 4; ++r) {
                int rr = crow + i * 16 + r;
                float v = a[r] + bi;
                if (HASRES) v += Res[(size_t)rr * Nstore + c];
                if (CBF16) Cb[(size_t)rr * Nstore + c] = f2bf(v);
                else       Cf[(size_t)rr * Nstore + c] = v;
            }
        }
    }
}

// ---------------------------------------------------------------------------
// 64x128-tile MFMA GEMM (wide), BK=64. Each wave: 32 rows x 64 cols.
// Used for QKV (bf16 out) and ISTFT (f32 out, batched via z strides).
template<bool CBF16>
__global__ __launch_bounds__(256) void gemm_wide(
    const ushort_t* __restrict__ Ah, const ushort_t* __restrict__ Bh,
    float* __restrict__ Cf, ushort_t* __restrict__ Cb,
    int Kloop, int Kstride, int Nstore, size_t az, size_t bz, size_t cz)
{
    const size_t zo = blockIdx.z;
    Ah += zo * az; Bh += zo * bz;
    if (CBF16) Cb += zo * cz; else Cf += zo * cz;

    const int f  = blockIdx.y * gridDim.x + blockIdx.x;
    const int tx = f / gridDim.y;
    const int ty = f - tx * gridDim.y;

    __shared__ __align__(16) ushort_t lds[12288];   // A 8KB + B 16KB
    ushort_t* AsH = lds;
    ushort_t* BsH = lds + 4096;

    const int tid  = threadIdx.x;
    const int wave = tid >> 6, lane = tid & 63;
    const int row0 = ty * 64;
    const int col0 = tx * 128;
    const int wr  = (wave >> 1) * 32;
    const int wcc = (wave & 1) * 64;

    const int sr = tid >> 3, js = tid & 7;
    const int jg = (js - (sr >> 1)) & 7;    // invariant under +32 rows
    const int d0 = tid * 16;

    const int kg = lane >> 4;
    const int lr = lane & 15;
    const int offA0 = fragoff(wr + lr, kg);
    const int offA1 = fragoff(wr + 16 + lr, kg);
    int offB[4];
#pragma unroll
    for (int j = 0; j < 4; ++j) offB[j] = fragoff(wcc + 16 * j + lr, kg);

    f32x4 acc[2][4];
#pragma unroll
    for (int i = 0; i < 2; ++i)
#pragma unroll
        for (int j = 0; j < 4; ++j) acc[i][j] = (f32x4){0.f,0.f,0.f,0.f};

    for (int k0 = 0; k0 < Kloop; k0 += 64) {
#pragma unroll
        for (int p = 0; p < 2; ++p)
            GLL16(Ah + (size_t)(row0 + p * 32 + sr) * Kstride + jg * 8 + k0,
                  (char*)AsH + p * 4096 + d0);
#pragma unroll
        for (int p = 0; p < 4; ++p)
            GLL16(Bh + (size_t)(col0 + p * 32 + sr) * Kstride + jg * 8 + k0,
                  (char*)BsH + p * 4096 + d0);
        __syncthreads();
#pragma unroll
        for (int h = 0; h < 2; ++h) {
            const int hx = h * 64;
            short8 a0 = *(const short8*)((const char*)AsH + (offA0 ^ hx));
            short8 a1 = *(const short8*)((const char*)AsH + (offA1 ^ hx));
            short8 b[4];
#pragma unroll
            for (int j = 0; j < 4; ++j)
                b[j] = *(const short8*)((const char*)BsH + (offB[j] ^ hx));
#pragma unroll
            for (int j = 0; j < 4; ++j) {
                acc[0][j] = __builtin_amdgcn_mfma_f32_16x16x32_bf16(a0, b[j], acc[0][j], 0, 0, 0);
                acc[1][j] = __builtin_amdgcn_mfma_f32_16x16x32_bf16(a1, b[j], acc[1][j], 0, 0, 0);
            }
        }
        __syncthreads();
    }

    const int crow = row0 + wr + (lane >> 4) * 4;
    const int ccol = col0 + wcc + lr;
#pragma unroll
    for (int i = 0; i < 2; ++i) {
#pragma unroll
        for (int j = 0; j < 4; ++j) {
            int c = ccol + j * 16;
            if (c >= Nstore) continue;
#pragma unroll
            for (int r = 0; r < 4; ++r) {
                int rr = crow + i * 16 + r;
                if (CBF16) Cb[(size_t)rr * Nstore + c] = f2bf(acc[i][j][r]);
                else       Cf[(size_t)rr * Nstore + c] = acc[i][j][r];
            }
        }
    }
}

// ---------------------------------------------------------------------------
// 64x128-tile fused gate/up GEMM + SwiGLU -> bf16 F. BK=64.
__global__ __launch_bounds__(256) void gemm_swiglu(
    const ushort_t* __restrict__ Ah,
    const ushort_t* __restrict__ Bg, const ushort_t* __restrict__ Bu,
    ushort_t* __restrict__ F, int K)
{
    const int f  = blockIdx.y * gridDim.x + blockIdx.x;
    const int tx = f / gridDim.y;
    const int ty = f - tx * gridDim.y;

    __shared__ __align__(16) ushort_t lds[20480];   // A 8KB + Bg 16KB + Bu 16KB
    ushort_t* AsH = lds;
    ushort_t* Bgs = lds + 4096;
    ushort_t* Bus = lds + 12288;

    const int tid  = threadIdx.x;
    const int wave = tid >> 6, lane = tid & 63;
    const int row0 = ty * 64;
    const int col0 = tx * 128;
    const int wr  = (wave >> 1) * 32;
    const int wcc = (wave & 1) * 64;

    const int sr = tid >> 3, js = tid & 7;
    const int jg = (js - (sr >> 1)) & 7;
    const int d0 = tid * 16;

    const int kg = lane >> 4;
    const int lr = lane & 15;
    const int offA0 = fragoff(wr + lr, kg);
    const int offA1 = fragoff(wr + 16 + lr, kg);
    int offB[4];
#pragma unroll
    for (int j = 0; j < 4; ++j) offB[j] = fragoff(wcc + 16 * j + lr, kg);

    f32x4 g[2][4], u[2][4];
#pragma unroll
    for (int i = 0; i < 2; ++i)
#pragma unroll
        for (int j = 0; j < 4; ++j) { g[i][j] = (f32x4){0.f,0.f,0.f,0.f}; u[i][j] = g[i][j]; }

    for (int k0 = 0; k0 < K; k0 += 64) {
#pragma unroll
        for (int p = 0; p < 2; ++p)
            GLL16(Ah + (size_t)(row0 + p * 32 + sr) * K + jg * 8 + k0,
                  (char*)AsH + p * 4096 + d0);
#pragma unroll
        for (int p = 0; p < 4; ++p) {
            const size_t src = (size_t)(col0 + p * 32 + sr) * K + jg * 8 + k0;
            GLL16(Bg + src, (char*)Bgs + p * 4096 + d0);
            GLL16(Bu + src, (char*)Bus + p * 4096 + d0);
        }
        __syncthreads();
#pragma unroll
        for (int h = 0; h < 2; ++h) {
            const int hx = h * 64;
            short8 a0 = *(const short8*)((const char*)AsH + (offA0 ^ hx));
            short8 a1 = *(const short8*)((const char*)AsH + (offA1 ^ hx));
#pragma unroll
            for (int j = 0; j < 4; ++j) {
                short8 bgj = *(const short8*)((const char*)Bgs + (offB[j] ^ hx));
                short8 buj = *(const short8*)((const char*)Bus + (offB[j] ^ hx));
                g[0][j] = __builtin_amdgcn_mfma_f32_16x16x32_bf16(a0, bgj, g[0][j], 0, 0, 0);
                g[1][j] = __builtin_amdgcn_mfma_f32_16x16x32_bf16(a1, bgj, g[1][j], 0, 0, 0);
                u[0][j] = __builtin_amdgcn_mfma_f32_16x16x32_bf16(a0, buj, u[0][j], 0, 0, 0);
                u[1][j] = __builtin_amdgcn_mfma_f32_16x16x32_bf16(a1, buj, u[1][j], 0, 0, 0);
            }
        }
        __syncthreads();
    }

    const int crow = row0 + wr + (lane >> 4) * 4;
    const int ccol = col0 + wcc + lr;
#pragma unroll
    for (int i = 0; i < 2; ++i) {
#pragma unroll
        for (int j = 0; j < 4; ++j) {
            int c = ccol + j * 16;
#pragma unroll
            for (int r = 0; r < 4; ++r) {
                int rr = crow + i * 16 + r;
                float gv = g[i][j][r];
                float v = (gv / (1.f + expf(-gv))) * u[i][j][r];
                F[(size_t)rr * FF_ + c] = f2bf(v);
            }
        }
    }
}

// ---------------------------------------------------------------------------
// Sliding-window causal attention on bf16 interleaved QKV [ROW][1536].
__global__ __launch_bounds__(256) void k_attn(const ushort_t* __restrict__ QKV,
                                              ushort_t* __restrict__ O)
{
    const int wv   = threadIdx.x >> 6;
    const int lane = threadIdx.x & 63;
    const int qi = lane >> 3;
    const int dg = lane & 7;
    const int nqb = S_ / 32;
    int blk  = blockIdx.x;
    int qblk = blk % nqb;
    int bh   = blk / nqb;
    int hh = bh & 7, bb = bh >> 3;
    int qp = qblk * 32 + wv * 8 + qi;
    const ushort_t* base = QKV + (size_t)bb * S_ * 1536 + hh * 64 + dg * 8;

    float q[8];
    {
        ushort8_t qv = *(const ushort8_t*)(base + (size_t)qp * 1536);
#pragma unroll
        for (int d = 0; d < 8; ++d) q[d] = bf2f(qv[d]) * 0.125f;
    }

    float sc[SWIN_];
    float mx = -3.0e38f;
#pragma unroll
    for (int jj = 0; jj < SWIN_; ++jj) {
        int j = qp - (SWIN_ - 1) + jj;
        int jc = j < 0 ? 0 : j;
        ushort8_t kv = *(const ushort8_t*)(base + (size_t)jc * 1536 + 512);
        float p = 0.f;
#pragma unroll
        for (int d = 0; d < 8; ++d) p += q[d] * bf2f(kv[d]);
        p += __shfl_xor(p, 1);
        p += __shfl_xor(p, 2);
        p += __shfl_xor(p, 4);
        p = (j >= 0) ? p : -1e30f;
        sc[jj] = p;
        mx = fmaxf(mx, p);
    }
    float den = 0.f;
#pragma unroll
    for (int jj = 0; jj < SWIN_; ++jj) { sc[jj] = __expf(sc[jj] - mx); den += sc[jj]; }
    float inv = 1.f / den;

    float acc[8] = {0.f,0.f,0.f,0.f,0.f,0.f,0.f,0.f};
#pragma unroll
    for (int jj = 0; jj < SWIN_; ++jj) {
        int j = qp - (SWIN_ - 1) + jj;
        int jc = j < 0 ? 0 : j;
        ushort8_t vv = *(const ushort8_t*)(base + (size_t)jc * 1536 + 1024);
        float p = sc[jj];
#pragma unroll
        for (int d = 0; d < 8; ++d) acc[d] += p * bf2f(vv[d]);
    }
    ushort8_t ov;
#pragma unroll
    for (int d = 0; d < 8; ++d) ov[d] = f2bf(acc[d] * inv);
    *(ushort8_t*)(O + (size_t)(bb * S_ + qp) * 512 + hh * 64 + dg * 8) = ov;
}

// ---------------------------------------------------------------------------
// Fused: (1) Yb f32 [ROW][1282] -> bf16 half-spectra Ysp2[z][ROW][KH_]
//        (2) bf16 half synthesis matrices M2[z][NHP2_][KH_]
__global__ __launch_bounds__(256) void k_specm(const float* __restrict__ Y,
                                               ushort_t* __restrict__ Yh,
                                               ushort_t* __restrict__ Mh)
{
    int idx = blockIdx.x * 256 + threadIdx.x;
    const int P1 = 2 * ROW_ * KH_;
    if (idx < P1) {
        int k  = idx % KH_;
        int rz = idx / KH_;
        int row = rz % ROW_;
        int z   = rz / ROW_;
        float v = 0.f;
        if (k < NBIN_) {
            float la = Y[(size_t)row * NC_ + k];
            float an = Y[(size_t)row * NC_ + NBIN_ + k];
            float sn, cs;
            sincosf(an, &sn, &cs);
            v = expf(la) * (z ? sn : cs);
        }
        Yh[idx] = f2bf(v);
    } else {
        idx -= P1;
        if (idx >= 2 * NHP2_ * KH_) return;
        int k  = idx % KH_;
        int nz = idx / KH_;
        int n  = nz % NHP2_;
        int z  = nz / NHP2_;
        float val = 0.f;
        if (k < NBIN_ && n < NBIN_) {
            int kn = (k * n) % NFFT_;
            float ang = (float)kn * TWO_PI_OVER_N;
            float ck = (k == 0 || k == NBIN_ - 1) ? 1.f : 2.f;
            float win = 0.5f * (1.f - cosf((float)n * TWO_PI_OVER_N));
            float sn, cs;
            sincosf(ang, &sn, &cs);
            val = (z ? sn : cs) * ck * win * (1.f / (float)NFFT_);
        }
        Mh[idx] = f2bf(val);
    }
}

// ---------------------------------------------------------------------------
// Overlap-add gather + inline envelope from half-spectrum results:
// FR[n] = C[n]-S[n] (n<=640), C[1280-n]+S[1280-n] otherwise.
__global__ __launch_bounds__(256) void k_overlap(const float* __restrict__ F2,
                                                 float* __restrict__ out)
{
    int idx = blockIdx.x * 256 + threadIdx.x;
    if (idx >= B_ * OUTL_) return;
    int j = idx % OUTL_;
    int b = idx / OUTL_;
    int m = j + PAD_;
    int smax = m / HOP_;            if (smax > S_ - 1) smax = S_ - 1;
    int smin = (m - (WIN_ - HOP_)) / HOP_;
    if (smin < 0) smin = 0;
    const float* FS = F2 + (size_t)ROW_ * NH_;
    float acc = 0.f, env = 0.f;
    for (int s = smin; s <= smax; ++s) {
        int off = m - s * HOP_;
        size_t row = (size_t)(b * S_ + s) * NH_;
        float v;
        if (off < NBIN_) v = F2[row + off] - FS[row + off];
        else             v = F2[row + (NFFT_ - off)] + FS[row + (NFFT_ - off)];
        acc += v;
        float w = 0.5f * (1.f - cosf((float)off * TWO_PI_OVER_N));
        env += w * w;
    }
    out[idx] = acc / env;
}

// ---------------------------------------------------------------------------
extern "C" void kernel_launch(void* const* d_in, const int* in_sizes, int n_in,
                              void* d_out, int out_size, void* d_ws, size_t ws_size,
                              hipStream_t stream)
{
    (void)in_sizes; (void)n_in; (void)out_size; (void)ws_size;
    const int*   codes = (const int*)  d_in[0];
    const float* emb   = (const float*)d_in[1];
    const float* ln1   = (const float*)d_in[2];
    const float* ln2   = (const float*)d_in[3];
    const float* fln   = (const float*)d_in[4];
    const float* wq    = (const float*)d_in[5];
    const float* wk    = (const float*)d_in[6];
    const float* wv    = (const float*)d_in[7];
    const float* wo    = (const float*)d_in[8];
    const float* wg    = (const float*)d_in[9];
    const float* wu    = (const float*)d_in[10];
    const float* wd    = (const float*)d_in[11];
    const float* lin_w = (const float*)d_in[12];
    const float* lin_b = (const float*)d_in[13];
    float* out = (float*)d_out;
    float* ws  = (float*)d_ws;

    // ---- workspace layout (f32 units; all 16B aligned) ----
    size_t o = 0;
    float*    X     = ws;                  o += (size_t)ROW_ * D_;            // f32
    ushort_t* QKVbf = (ushort_t*)(ws + o); o += (size_t)ROW_ * 1536 / 2;      // bf16
    ushort_t* Hb    = (ushort_t*)(ws + o); o += (size_t)ROW_ * D_ / 2;
    float*    OFY   = ws + o;              o += (size_t)ROW_ * NC_;           // region
    ushort_t* O     = (ushort_t*)OFY;                       // [ROW][512] bf16
    ushort_t* F     = (ushort_t*)(OFY + (size_t)ROW_ * D_ / 2);  // [ROW][2048] bf16
    float*    Yb    = OFY;                                  // [ROW][1282] f32 (after loop)
    float*    F2    = OFY;                                  // [2][ROW][641] f32 (after spec)
    ushort_t* wqkvT = (ushort_t*)(ws + o); o += (size_t)NL_ * 1536 * D_ / 2;
    ushort_t* woT   = (ushort_t*)(ws + o); o += (size_t)NL_ * D_ * D_ / 2;
    ushort_t* M2_h  = wqkvT;                                // [2][NHP2_][KH_] (after loop)
    ushort_t* wguT  = (ushort_t*)(ws + o); o += (size_t)NL_ * 4096 * D_ / 2;
    ushort_t* Ysp_h = wguT;                                 // [2][ROW][KH_] (after loop)
    ushort_t* wdT   = (ushort_t*)(ws + o); o += (size_t)NL_ * D_ * FF_ / 2;
    ushort_t* Hlo   = wdT;                                  // [ROW][512] (after loop)
    ushort_t* linTh = (ushort_t*)(ws + o); o += (size_t)NPADL * D_ / 2;
    ushort_t* linTl = (ushort_t*)(ws + o); o += (size_t)NPADL * D_ / 2;
    float*    Pp    = ws + o;              o += (size_t)2 * ROW_ * D_;        // split-K partials

    dim3 blk(256);

    k_embed<<<dim3((B_ * T_ * D_) / 256), blk, 0, stream>>>(codes, emb, X);

    // weight transpose-casts (batched over layers)
    k_castT<<<dim3(16, 16, NL_), blk, 0, stream>>>(wq, wqkvT,            nullptr, D_, D_, (long)D_*D_, (long)1536*D_);
    k_castT<<<dim3(16, 16, NL_), blk, 0, stream>>>(wk, wqkvT + 512*512,  nullptr, D_, D_, (long)D_*D_, (long)1536*D_);
    k_castT<<<dim3(16, 16, NL_), blk, 0, stream>>>(wv, wqkvT + 1024*512, nullptr, D_, D_, (long)D_*D_, (long)1536*D_);
    k_castT<<<dim3(16, 16, NL_), blk, 0, stream>>>(wo, woT,              nullptr, D_, D_, (long)D_*D_, (long)D_*D_);
    k_castT<<<dim3(64, 16, NL_), blk, 0, stream>>>(wg, wguT,             nullptr, D_, FF_, (long)D_*FF_, (long)4096*D_);
    k_castT<<<dim3(64, 16, NL_), blk, 0, stream>>>(wu, wguT + 2048*512,  nullptr, D_, FF_, (long)D_*FF_, (long)4096*D_);
    k_castT<<<dim3(16, 64, NL_), blk, 0, stream>>>(wd, wdT,              nullptr, FF_, D_, (long)FF_*D_, (long)D_*FF_);
    k_castT<<<dim3(NPADL/32, 16, 1), blk, 0, stream>>>(lin_w, linTh, linTl, D_, NC_, 0, 0);

    for (int l = 0; l < NL_; ++l) {
        // rmsnorm1: layers >0 fold in the previous wd's split-K partials
        k_rmsnorm<<<dim3(ROW_), blk, 0, stream>>>(
            X, (l == 0) ? nullptr : Pp, Pp + (size_t)ROW_ * D_, ln1 + l * D_, Hb, nullptr);
        gemm_wide<true><<<dim3(12, 48), blk, 0, stream>>>(
            Hb, wqkvT + (size_t)l * 1536 * D_, nullptr, QKVbf, D_, D_, 1536, 0, 0, 0);
        k_attn<<<dim3(B_ * H_ * (S_ / 32)), blk, 0, stream>>>(QKVbf, O);
        gemm_mfma<false,false,true,false><<<dim3(8, 48), blk, 0, stream>>>(
            O, nullptr, woT + (size_t)l * D_ * D_, nullptr,
            X, nullptr, X, nullptr, D_, D_, D_, 0, 0, 0);
        k_rmsnorm<<<dim3(ROW_), blk, 0, stream>>>(X, nullptr, nullptr, ln2 + l * D_, Hb, nullptr);
        gemm_swiglu<<<dim3(16, 48), blk, 0, stream>>>(
            Hb, wguT + (size_t)l * 4096 * D_, wguT + (size_t)l * 4096 * D_ + (size_t)2048 * D_, F, D_);
        // wd: split-K x2 -> partials Pp[0], Pp[1]; folded by next rmsnorm
        gemm_mfma<false,false,false,false><<<dim3(8, 48, 2), blk, 0, stream>>>(
            F, nullptr, wdT + (size_t)l * D_ * FF_, nullptr,
            nullptr, nullptr, Pp, nullptr, FF_ / 2, FF_, D_,
            (size_t)(FF_ / 2), (size_t)(FF_ / 2), (size_t)ROW_ * D_);
    }

    k_rmsnorm<<<dim3(ROW_), blk, 0, stream>>>(
        X, Pp, Pp + (size_t)ROW_ * D_, fln, Hb, Hlo);
    gemm_mfma<true,false,false,true><<<dim3(NPADL/64, 48), blk, 0, stream>>>(
        Hb, Hlo, linTh, linTl, nullptr, lin_b, Yb, nullptr, D_, D_, NC_, 0, 0, 0);
    {
        int total = 2 * ROW_ * KH_ + 2 * NHP2_ * KH_;
        k_specm<<<dim3((total + 255) / 256), blk, 0, stream>>>(Yb, Ysp_h, M2_h);
    }
    gemm_wide<false><<<dim3(NHP2_/128, 48, 2), blk, 0, stream>>>(
        Ysp_h, M2_h, F2, nullptr, KH_, KH_, NH_,
        (size_t)ROW_ * KH_, (size_t)NHP2_ * KH_, (size_t)ROW_ * NH_);
    k_overlap<<<dim3((B_ * OUTL_ + 255) / 256), blk, 0, stream>>>(F2, out);
}

// Round 9
// 654.218 us; speedup vs baseline: 1.0205x; 1.0205x over previous
//
#include <hip/hip_runtime.h>
#include <math.h>

// Problem constants (LFM2AudioDetokenizer)
#define B_    2
#define T_    256
#define S_    1536      // T*6
#define D_    512
#define H_    8
#define DH_   64
#define FF_   2048
#define V_    2048
#define NL_   4
#define NFFT_ 1280
#define HOP_  320
#define WIN_  1280
#define NBIN_ 641
#define NC_   1282
#define NPADL 1344      // 1282 padded to mult of 64 (final-linear col tiles)
#define PAD_  480
#define OUTL_ 491520    // (S-1)*HOP + WIN - 2*PAD
#define SWIN_ 30
#define ROW_  (B_ * S_) // 3072
// Half-spectrum ISTFT (cos/sin symmetry) dims
#define NH_   641       // output cols n = 0..640
#define KH_   704       // K = 641 padded to mult of 64
#define NHP2_ 768       // B rows padded to mult of 128 (wide tiles)

#define TWO_PI_OVER_N 0.004908738521234052f   // 2*pi/1280

typedef unsigned short ushort_t;
typedef __attribute__((ext_vector_type(8))) short short8;
typedef __attribute__((ext_vector_type(8))) unsigned short ushort8_t;
typedef __attribute__((ext_vector_type(4))) float f32x4;

__device__ __forceinline__ ushort_t f2bf(float x) {
    unsigned int u = __builtin_bit_cast(unsigned int, x);
    u = (u + 0x7fffu + ((u >> 16) & 1u)) >> 16;
    return (ushort_t)u;
}
__device__ __forceinline__ float bf2f(ushort_t h) {
    unsigned int u = ((unsigned int)h) << 16;
    return __builtin_bit_cast(float, u);
}

#define GLL16(gp, sp) \
    __builtin_amdgcn_global_load_lds((const __attribute__((address_space(1))) void*)(gp), \
                                     (__attribute__((address_space(3))) void*)(sp), 16, 0, 0)

// BK=64 swizzled LDS row: 128B = 8 x 16B slots; slot = (jg + (r>>1)) & 7.
__device__ __forceinline__ int fragoff(int r, int kg) {
    return r * 128 + (((kg + (r >> 1)) & 7) * 16);
}

// ---------------------------------------------------------------------------
__global__ __launch_bounds__(256) void k_embed(const int* __restrict__ codes,
                                               const float* __restrict__ emb,
                                               float* __restrict__ X)
{
    int idx = blockIdx.x * 256 + threadIdx.x;
    int d  = idx & (D_ - 1);
    int bt = idx >> 9;
    int t  = bt & (T_ - 1);
    int b  = bt >> 8;
    float s = 0.f;
#pragma unroll
    for (int cb = 0; cb < 8; ++cb) {
        int code = codes[(b * 8 + cb) * T_ + t];
        s += emb[(size_t)(cb * V_ + code) * D_ + d];
    }
    s *= 0.125f;
    float* xp = X + (size_t)(b * S_ + t * 6) * D_ + d;
#pragma unroll
    for (int r = 0; r < 6; ++r) xp[(size_t)r * D_] = s;
}

// ---------------------------------------------------------------------------
// RMSNorm over D=512 -> bf16. Optional: fuse partial-sum X += P0+P1 (split-K
// down-proj) with X write-back; optional lo output for split consumers.
__global__ __launch_bounds__(256) void k_rmsnorm(float* __restrict__ X,
                                                 const float* __restrict__ P0,
                                                 const float* __restrict__ P1,
                                                 const float* __restrict__ w,
                                                 ushort_t* __restrict__ Hh,
                                                 ushort_t* __restrict__ Hl)
{
    int row = blockIdx.x;
    int tid = threadIdx.x;
    float* x = X + (size_t)row * D_;
    float v0 = x[tid], v1 = x[tid + 256];
    if (P0) {
        size_t b = (size_t)row * D_;
        v0 += P0[b + tid] + P1[b + tid];
        v1 += P0[b + tid + 256] + P1[b + tid + 256];
        x[tid] = v0; x[tid + 256] = v1;
    }
    float ss = v0 * v0 + v1 * v1;
#pragma unroll
    for (int m = 1; m < 64; m <<= 1) ss += __shfl_xor(ss, m);
    __shared__ float red[4];
    if ((tid & 63) == 0) red[tid >> 6] = ss;
    __syncthreads();
    float tot = red[0] + red[1] + red[2] + red[3];
    float sc = rsqrtf(tot * (1.f / (float)D_) + 1e-5f);
    float y0 = v0 * sc * w[tid];
    float y1 = v1 * sc * w[tid + 256];
    ushort_t h0 = f2bf(y0), h1 = f2bf(y1);
    Hh[(size_t)row * D_ + tid]       = h0;
    Hh[(size_t)row * D_ + tid + 256] = h1;
    if (Hl) {
        Hl[(size_t)row * D_ + tid]       = f2bf(y0 - bf2f(h0));
        Hl[(size_t)row * D_ + tid + 256] = f2bf(y1 - bf2f(h1));
    }
}

// ---------------------------------------------------------------------------
// Transpose-cast f32 [K,N] -> bf16 [Npad,K] (rows >= N zero-filled).
__global__ __launch_bounds__(256) void k_castT(const float* __restrict__ src,
                                               ushort_t* __restrict__ dh,
                                               ushort_t* __restrict__ dl,
                                               int K, int N,
                                               long srcBatchStride, long dstBatchStride)
{
    src += (size_t)blockIdx.z * srcBatchStride;
    dh  += (size_t)blockIdx.z * dstBatchStride;
    if (dl) dl += (size_t)blockIdx.z * dstBatchStride;
    __shared__ float t[32][33];
    int n0 = blockIdx.x * 32, k0 = blockIdx.y * 32;
    int tx = threadIdx.x & 31, ty = threadIdx.x >> 5;   // 32 x 8
#pragma unroll
    for (int i = 0; i < 4; ++i) {
        int k = k0 + ty + 8 * i, n = n0 + tx;
        t[ty + 8 * i][tx] = (n < N) ? src[(size_t)k * N + n] : 0.f;
    }
    __syncthreads();
#pragma unroll
    for (int i = 0; i < 4; ++i) {
        int n = n0 + ty + 8 * i;
        float v = t[tx][ty + 8 * i];
        ushort_t h = f2bf(v);
        dh[(size_t)n * K + k0 + tx] = h;
        if (dl) dl[(size_t)n * K + k0 + tx] = f2bf(v - bf2f(h));
    }
}

// ---------------------------------------------------------------------------
// 64x64-tile MFMA GEMM, BK=64, XCD swizzle. SPLIT: bf16x2. Kloop may be a
// slice of Kstride (split-K via blockIdx.z + az/bz/cz pointer strides).
template<bool SPLIT, bool CBF16, bool HASRES, bool HASBIAS>
__global__ __launch_bounds__(256) void gemm_mfma(
    const ushort_t* __restrict__ Ah, const ushort_t* __restrict__ Al,
    const ushort_t* __restrict__ Bh, const ushort_t* __restrict__ Bl,
    const float* __restrict__ Res, const float* __restrict__ bias,
    float* __restrict__ Cf, ushort_t* __restrict__ Cb,
    int Kloop, int Kstride, int Nstore, size_t az, size_t bz, size_t cz)
{
    const size_t zo = blockIdx.z;
    Ah += zo * az; Bh += zo * bz;
    if (SPLIT) { Al += zo * az; Bl += zo * bz; }
    if (CBF16) Cb += zo * cz; else Cf += zo * cz;

    const int f  = blockIdx.y * gridDim.x + blockIdx.x;
    const int tx = f / gridDim.y;
    const int ty = f - tx * gridDim.y;

    __shared__ __align__(16) ushort_t lds[SPLIT ? 16384 : 8192];
    ushort_t* AsH = lds;            // 64 rows x 128B = 8KB
    ushort_t* BsH = lds + 4096;

    const int tid  = threadIdx.x;
    const int wave = tid >> 6, lane = tid & 63;
    const int row0 = ty * 64;
    const int col0 = tx * 64;
    const int wr = (wave >> 1) * 32, wc = (wave & 1) * 32;

    const int sr0 = tid >> 3, js = tid & 7;
    const int jg  = (js - (sr0 >> 1)) & 7;    // same for +32 rows (16 ≡ 0 mod 8)
    const size_t aSrc0 = (size_t)(row0 + sr0) * Kstride + jg * 8;
    const size_t aSrc1 = (size_t)(row0 + 32 + sr0) * Kstride + jg * 8;
    const size_t bSrc0 = (size_t)(col0 + sr0) * Kstride + jg * 8;
    const size_t bSrc1 = (size_t)(col0 + 32 + sr0) * Kstride + jg * 8;
    const int d0 = tid * 16, d1 = d0 + 4096;

    const int kg = lane >> 4;
    const int lr = lane & 15;
    const int offA0 = fragoff(wr + lr, kg);
    const int offA1 = fragoff(wr + 16 + lr, kg);
    const int offB0 = fragoff(wc + lr, kg);
    const int offB1 = fragoff(wc + 16 + lr, kg);

    f32x4 acc00 = {0.f,0.f,0.f,0.f}, acc01 = acc00, acc10 = acc00, acc11 = acc00;

    for (int k0 = 0; k0 < Kloop; k0 += 64) {
        GLL16(Ah + aSrc0 + k0, (char*)AsH + d0);
        GLL16(Ah + aSrc1 + k0, (char*)AsH + d1);
        GLL16(Bh + bSrc0 + k0, (char*)BsH + d0);
        GLL16(Bh + bSrc1 + k0, (char*)BsH + d1);
        if constexpr (SPLIT) {
            GLL16(Al + aSrc0 + k0, (char*)(lds + 8192)  + d0);
            GLL16(Al + aSrc1 + k0, (char*)(lds + 8192)  + d1);
            GLL16(Bl + bSrc0 + k0, (char*)(lds + 12288) + d0);
            GLL16(Bl + bSrc1 + k0, (char*)(lds + 12288) + d1);
        }
        __syncthreads();
#pragma unroll
        for (int h = 0; h < 2; ++h) {
            const int hx = h * 64;
            short8 a0 = *(const short8*)((const char*)AsH + (offA0 ^ hx));
            short8 a1 = *(const short8*)((const char*)AsH + (offA1 ^ hx));
            short8 b0 = *(const short8*)((const char*)BsH + (offB0 ^ hx));
            short8 b1 = *(const short8*)((const char*)BsH + (offB1 ^ hx));
            acc00 = __builtin_amdgcn_mfma_f32_16x16x32_bf16(a0, b0, acc00, 0, 0, 0);
            acc01 = __builtin_amdgcn_mfma_f32_16x16x32_bf16(a0, b1, acc01, 0, 0, 0);
            acc10 = __builtin_amdgcn_mfma_f32_16x16x32_bf16(a1, b0, acc10, 0, 0, 0);
            acc11 = __builtin_amdgcn_mfma_f32_16x16x32_bf16(a1, b1, acc11, 0, 0, 0);
            if constexpr (SPLIT) {
                short8 al0 = *(const short8*)((const char*)(lds + 8192)  + (offA0 ^ hx));
                short8 al1 = *(const short8*)((const char*)(lds + 8192)  + (offA1 ^ hx));
                short8 bl0 = *(const short8*)((const char*)(lds + 12288) + (offB0 ^ hx));
                short8 bl1 = *(const short8*)((const char*)(lds + 12288) + (offB1 ^ hx));
                acc00 = __builtin_amdgcn_mfma_f32_16x16x32_bf16(a0, bl0, acc00, 0, 0, 0);
                acc00 = __builtin_amdgcn_mfma_f32_16x16x32_bf16(al0, b0, acc00, 0, 0, 0);
                acc01 = __builtin_amdgcn_mfma_f32_16x16x32_bf16(a0, bl1, acc01, 0, 0, 0);
                acc01 = __builtin_amdgcn_mfma_f32_16x16x32_bf16(al0, b1, acc01, 0, 0, 0);
                acc10 = __builtin_amdgcn_mfma_f32_16x16x32_bf16(a1, bl0, acc10, 0, 0, 0);
                acc10 = __builtin_amdgcn_mfma_f32_16x16x32_bf16(al1, b0, acc10, 0, 0, 0);
                acc11 = __builtin_amdgcn_mfma_f32_16x16x32_bf16(a1, bl1, acc11, 0, 0, 0);
                acc11 = __builtin_amdgcn_mfma_f32_16x16x32_bf16(al1, b1, acc11, 0, 0, 0);
            }
        }
        __syncthreads();
    }

    const int crow = row0 + wr + (lane >> 4) * 4;
    const int ccol = col0 + wc + lr;
#pragma unroll
    for (int i = 0; i < 2; ++i) {
#pragma unroll
        for (int j = 0; j < 2; ++j) {
            const f32x4 a = (i == 0) ? (j == 0 ? acc00 : acc01) : (j == 0 ? acc10 : acc11);
            int c = ccol + j * 16;
            if (c >= Nstore) continue;
            float bi = HASBIAS ? bias[c] : 0.f;
#pragma unroll
            for (int r = 0; r < 4; ++r) {
                int rr = crow + i * 16 + r;
                float v = a[r] + bi;
                if (HASRES) v += Res[(size_t)rr * Nstore + c];
                if (CBF16) Cb[(size_t)rr * Nstore + c] = f2bf(v);
                else       Cf[(size_t)rr * Nstore + c] = v;
            }
        }
    }
}

// ---------------------------------------------------------------------------
// 64x128-tile MFMA GEMM (wide), BK=64. Each wave: 32 rows x 64 cols.
// Used for QKV (bf16 out) and ISTFT (f32 out, batched via z strides).
template<bool CBF16>
__global__ __launch_bounds__(256) void gemm_wide(
    const ushort_t* __restrict__ Ah, const ushort_t* __restrict__ Bh,
    float* __restrict__ Cf, ushort_t* __restrict__ Cb,
    int Kloop, int Kstride, int Nstore, size_t az, size_t bz, size_t cz)
{
    const size_t zo = blockIdx.z;
    Ah += zo * az; Bh += zo * bz;
    if (CBF16) Cb += zo * cz; else Cf += zo * cz;

    const int f  = blockIdx.y * gridDim.x + blockIdx.x;
    const int tx = f / gridDim.y;
    const int ty = f - tx * gridDim.y;

    __shared__ __align__(16) ushort_t lds[12288];   // A 8KB + B 16KB
    ushort_t* AsH = lds;
    ushort_t* BsH = lds + 4096;

    const int tid  = threadIdx.x;
    const int wave = tid >> 6, lane = tid & 63;
    const int row0 = ty * 64;
    const int col0 = tx * 128;
    const int wr  = (wave >> 1) * 32;
    const int wcc = (wave & 1) * 64;

    const int sr = tid >> 3, js = tid & 7;
    const int jg = (js - (sr >> 1)) & 7;    // invariant under +32 rows
    const int d0 = tid * 16;

    const int kg = lane >> 4;
    const int lr = lane & 15;
    const int offA0 = fragoff(wr + lr, kg);
    const int offA1 = fragoff(wr + 16 + lr, kg);
    int offB[4];
#pragma unroll
    for (int j = 0; j < 4; ++j) offB[j] = fragoff(wcc + 16 * j + lr, kg);

    f32x4 acc[2][4];
#pragma unroll
    for (int i = 0; i < 2; ++i)
#pragma unroll
        for (int j = 0; j < 4; ++j) acc[i][j] = (f32x4){0.f,0.f,0.f,0.f};

    for (int k0 = 0; k0 < Kloop; k0 += 64) {
#pragma unroll
        for (int p = 0; p < 2; ++p)
            GLL16(Ah + (size_t)(row0 + p * 32 + sr) * Kstride + jg * 8 + k0,
                  (char*)AsH + p * 4096 + d0);
#pragma unroll
        for (int p = 0; p < 4; ++p)
            GLL16(Bh + (size_t)(col0 + p * 32 + sr) * Kstride + jg * 8 + k0,
                  (char*)BsH + p * 4096 + d0);
        __syncthreads();
#pragma unroll
        for (int h = 0; h < 2; ++h) {
            const int hx = h * 64;
            short8 a0 = *(const short8*)((const char*)AsH + (offA0 ^ hx));
            short8 a1 = *(const short8*)((const char*)AsH + (offA1 ^ hx));
            short8 b[4];
#pragma unroll
            for (int j = 0; j < 4; ++j)
                b[j] = *(const short8*)((const char*)BsH + (offB[j] ^ hx));
#pragma unroll
            for (int j = 0; j < 4; ++j) {
                acc[0][j] = __builtin_amdgcn_mfma_f32_16x16x32_bf16(a0, b[j], acc[0][j], 0, 0, 0);
                acc[1][j] = __builtin_amdgcn_mfma_f32_16x16x32_bf16(a1, b[j], acc[1][j], 0, 0, 0);
            }
        }
        __syncthreads();
    }

    const int crow = row0 + wr + (lane >> 4) * 4;
    const int ccol = col0 + wcc + lr;
#pragma unroll
    for (int i = 0; i < 2; ++i) {
#pragma unroll
        for (int j = 0; j < 4; ++j) {
            int c = ccol + j * 16;
            if (c >= Nstore) continue;
#pragma unroll
            for (int r = 0; r < 4; ++r) {
                int rr = crow + i * 16 + r;
                if (CBF16) Cb[(size_t)rr * Nstore + c] = f2bf(acc[i][j][r]);
                else       Cf[(size_t)rr * Nstore + c] = acc[i][j][r];
            }
        }
    }
}

// ---------------------------------------------------------------------------
// 64x64-tile fused gate/up GEMM + SwiGLU -> bf16 F. BK=64, 24KB LDS,
// grid 32x48 = 1536 blocks (6/CU). [R6-proven shape; R8's 64x128 regressed:
// 40KB LDS -> 3 blocks/CU, latency-bound at MfmaUtil 9%.]
__global__ __launch_bounds__(256) void gemm_swiglu(
    const ushort_t* __restrict__ Ah,
    const ushort_t* __restrict__ Bg, const ushort_t* __restrict__ Bu,
    ushort_t* __restrict__ F, int K)
{
    const int f  = blockIdx.y * gridDim.x + blockIdx.x;
    const int tx = f / gridDim.y;
    const int ty = f - tx * gridDim.y;

    __shared__ __align__(16) ushort_t lds[12288];   // A 8KB + Bg 8KB + Bu 8KB
    ushort_t* As  = lds;
    ushort_t* Bgs = lds + 4096;
    ushort_t* Bus = lds + 8192;

    const int tid  = threadIdx.x;
    const int wave = tid >> 6, lane = tid & 63;
    const int row0 = ty * 64;
    const int col0 = tx * 64;
    const int wr = (wave >> 1) * 32, wc = (wave & 1) * 32;

    const int sr0 = tid >> 3, js = tid & 7;
    const int jg  = (js - (sr0 >> 1)) & 7;
    const size_t aSrc0 = (size_t)(row0 + sr0) * K + jg * 8;
    const size_t aSrc1 = (size_t)(row0 + 32 + sr0) * K + jg * 8;
    const size_t bSrc0 = (size_t)(col0 + sr0) * K + jg * 8;
    const size_t bSrc1 = (size_t)(col0 + 32 + sr0) * K + jg * 8;
    const int d0 = tid * 16, d1 = d0 + 4096;

    const int kg = lane >> 4;
    const int lr = lane & 15;
    const int offA0 = fragoff(wr + lr, kg);
    const int offA1 = fragoff(wr + 16 + lr, kg);
    const int offB0 = fragoff(wc + lr, kg);
    const int offB1 = fragoff(wc + 16 + lr, kg);

    f32x4 g00 = {0.f,0.f,0.f,0.f}, g01 = g00, g10 = g00, g11 = g00;
    f32x4 u00 = g00, u01 = g00, u10 = g00, u11 = g00;

    for (int k0 = 0; k0 < K; k0 += 64) {
        GLL16(Ah + aSrc0 + k0, (char*)As  + d0);
        GLL16(Ah + aSrc1 + k0, (char*)As  + d1);
        GLL16(Bg + bSrc0 + k0, (char*)Bgs + d0);
        GLL16(Bg + bSrc1 + k0, (char*)Bgs + d1);
        GLL16(Bu + bSrc0 + k0, (char*)Bus + d0);
        GLL16(Bu + bSrc1 + k0, (char*)Bus + d1);
        __syncthreads();
#pragma unroll
        for (int h = 0; h < 2; ++h) {
            const int hx = h * 64;
            short8 a0  = *(const short8*)((const char*)As  + (offA0 ^ hx));
            short8 a1  = *(const short8*)((const char*)As  + (offA1 ^ hx));
            short8 bg0 = *(const short8*)((const char*)Bgs + (offB0 ^ hx));
            short8 bg1 = *(const short8*)((const char*)Bgs + (offB1 ^ hx));
            short8 bu0 = *(const short8*)((const char*)Bus + (offB0 ^ hx));
            short8 bu1 = *(const short8*)((const char*)Bus + (offB1 ^ hx));
            g00 = __builtin_amdgcn_mfma_f32_16x16x32_bf16(a0, bg0, g00, 0, 0, 0);
            g01 = __builtin_amdgcn_mfma_f32_16x16x32_bf16(a0, bg1, g01, 0, 0, 0);
            g10 = __builtin_amdgcn_mfma_f32_16x16x32_bf16(a1, bg0, g10, 0, 0, 0);
            g11 = __builtin_amdgcn_mfma_f32_16x16x32_bf16(a1, bg1, g11, 0, 0, 0);
            u00 = __builtin_amdgcn_mfma_f32_16x16x32_bf16(a0, bu0, u00, 0, 0, 0);
            u01 = __builtin_amdgcn_mfma_f32_16x16x32_bf16(a0, bu1, u01, 0, 0, 0);
            u10 = __builtin_amdgcn_mfma_f32_16x16x32_bf16(a1, bu0, u10, 0, 0, 0);
            u11 = __builtin_amdgcn_mfma_f32_16x16x32_bf16(a1, bu1, u11, 0, 0, 0);
        }
        __syncthreads();
    }

    const int crow = row0 + wr + (lane >> 4) * 4;
    const int ccol = col0 + wc + lr;
#pragma unroll
    for (int i = 0; i < 2; ++i) {
#pragma unroll
        for (int j = 0; j < 2; ++j) {
            const f32x4 g = (i == 0) ? (j == 0 ? g00 : g01) : (j == 0 ? g10 : g11);
            const f32x4 u = (i == 0) ? (j == 0 ? u00 : u01) : (j == 0 ? u10 : u11);
            int c = ccol + j * 16;
#pragma unroll
            for (int r = 0; r < 4; ++r) {
                int rr = crow + i * 16 + r;
                float gv = g[r];
                float v = (gv / (1.f + expf(-gv))) * u[r];
                F[(size_t)rr * FF_ + c] = f2bf(v);
            }
        }
    }
}

// ---------------------------------------------------------------------------
// Sliding-window causal attention on bf16 interleaved QKV [ROW][1536].
__global__ __launch_bounds__(256) void k_attn(const ushort_t* __restrict__ QKV,
                                              ushort_t* __restrict__ O)
{
    const int wv   = threadIdx.x >> 6;
    const int lane = threadIdx.x & 63;
    const int qi = lane >> 3;
    const int dg = lane & 7;
    const int nqb = S_ / 32;
    int blk  = blockIdx.x;
    int qblk = blk % nqb;
    int bh   = blk / nqb;
    int hh = bh & 7, bb = bh >> 3;
    int qp = qblk * 32 + wv * 8 + qi;
    const ushort_t* base = QKV + (size_t)bb * S_ * 1536 + hh * 64 + dg * 8;

    float q[8];
    {
        ushort8_t qv = *(const ushort8_t*)(base + (size_t)qp * 1536);
#pragma unroll
        for (int d = 0; d < 8; ++d) q[d] = bf2f(qv[d]) * 0.125f;
    }

    float sc[SWIN_];
    float mx = -3.0e38f;
#pragma unroll
    for (int jj = 0; jj < SWIN_; ++jj) {
        int j = qp - (SWIN_ - 1) + jj;
        int jc = j < 0 ? 0 : j;
        ushort8_t kv = *(const ushort8_t*)(base + (size_t)jc * 1536 + 512);
        float p = 0.f;
#pragma unroll
        for (int d = 0; d < 8; ++d) p += q[d] * bf2f(kv[d]);
        p += __shfl_xor(p, 1);
        p += __shfl_xor(p, 2);
        p += __shfl_xor(p, 4);
        p = (j >= 0) ? p : -1e30f;
        sc[jj] = p;
        mx = fmaxf(mx, p);
    }
    float den = 0.f;
#pragma unroll
    for (int jj = 0; jj < SWIN_; ++jj) { sc[jj] = __expf(sc[jj] - mx); den += sc[jj]; }
    float inv = 1.f / den;

    float acc[8] = {0.f,0.f,0.f,0.f,0.f,0.f,0.f,0.f};
#pragma unroll
    for (int jj = 0; jj < SWIN_; ++jj) {
        int j = qp - (SWIN_ - 1) + jj;
        int jc = j < 0 ? 0 : j;
        ushort8_t vv = *(const ushort8_t*)(base + (size_t)jc * 1536 + 1024);
        float p = sc[jj];
#pragma unroll
        for (int d = 0; d < 8; ++d) acc[d] += p * bf2f(vv[d]);
    }
    ushort8_t ov;
#pragma unroll
    for (int d = 0; d < 8; ++d) ov[d] = f2bf(acc[d] * inv);
    *(ushort8_t*)(O + (size_t)(bb * S_ + qp) * 512 + hh * 64 + dg * 8) = ov;
}

// ---------------------------------------------------------------------------
// Fused: (1) Yb f32 [ROW][1282] -> bf16 half-spectra Ysp2[z][ROW][KH_]
//        (2) bf16 half synthesis matrices M2[z][NHP2_][KH_]
__global__ __launch_bounds__(256) void k_specm(const float* __restrict__ Y,
                                               ushort_t* __restrict__ Yh,
                                               ushort_t* __restrict__ Mh)
{
    int idx = blockIdx.x * 256 + threadIdx.x;
    const int P1 = 2 * ROW_ * KH_;
    if (idx < P1) {
        int k  = idx % KH_;
        int rz = idx / KH_;
        int row = rz % ROW_;
        int z   = rz / ROW_;
        float v = 0.f;
        if (k < NBIN_) {
            float la = Y[(size_t)row * NC_ + k];
            float an = Y[(size_t)row * NC_ + NBIN_ + k];
            float sn, cs;
            sincosf(an, &sn, &cs);
            v = expf(la) * (z ? sn : cs);
        }
        Yh[idx] = f2bf(v);
    } else {
        idx -= P1;
        if (idx >= 2 * NHP2_ * KH_) return;
        int k  = idx % KH_;
        int nz = idx / KH_;
        int n  = nz % NHP2_;
        int z  = nz / NHP2_;
        float val = 0.f;
        if (k < NBIN_ && n < NBIN_) {
            int kn = (k * n) % NFFT_;
            float ang = (float)kn * TWO_PI_OVER_N;
            float ck = (k == 0 || k == NBIN_ - 1) ? 1.f : 2.f;
            float win = 0.5f * (1.f - cosf((float)n * TWO_PI_OVER_N));
            float sn, cs;
            sincosf(ang, &sn, &cs);
            val = (z ? sn : cs) * ck * win * (1.f / (float)NFFT_);
        }
        Mh[idx] = f2bf(val);
    }
}

// ---------------------------------------------------------------------------
// Overlap-add gather + inline envelope from half-spectrum results:
// FR[n] = C[n]-S[n] (n<=640), C[1280-n]+S[1280-n] otherwise.
__global__ __launch_bounds__(256) void k_overlap(const float* __restrict__ F2,
                                                 float* __restrict__ out)
{
    int idx = blockIdx.x * 256 + threadIdx.x;
    if (idx >= B_ * OUTL_) return;
    int j = idx % OUTL_;
    int b = idx / OUTL_;
    int m = j + PAD_;
    int smax = m / HOP_;            if (smax > S_ - 1) smax = S_ - 1;
    int smin = (m - (WIN_ - HOP_)) / HOP_;
    if (smin < 0) smin = 0;
    const float* FS = F2 + (size_t)ROW_ * NH_;
    float acc = 0.f, env = 0.f;
    for (int s = smin; s <= smax; ++s) {
        int off = m - s * HOP_;
        size_t row = (size_t)(b * S_ + s) * NH_;
        float v;
        if (off < NBIN_) v = F2[row + off] - FS[row + off];
        else             v = F2[row + (NFFT_ - off)] + FS[row + (NFFT_ - off)];
        acc += v;
        float w = 0.5f * (1.f - cosf((float)off * TWO_PI_OVER_N));
        env += w * w;
    }
    out[idx] = acc / env;
}

// ---------------------------------------------------------------------------
extern "C" void kernel_launch(void* const* d_in, const int* in_sizes, int n_in,
                              void* d_out, int out_size, void* d_ws, size_t ws_size,
                              hipStream_t stream)
{
    (void)in_sizes; (void)n_in; (void)out_size; (void)ws_size;
    const int*   codes = (const int*)  d_in[0];
    const float* emb   = (const float*)d_in[1];
    const float* ln1   = (const float*)d_in[2];
    const float* ln2   = (const float*)d_in[3];
    const float* fln   = (const float*)d_in[4];
    const float* wq    = (const float*)d_in[5];
    const float* wk    = (const float*)d_in[6];
    const float* wv    = (const float*)d_in[7];
    const float* wo    = (const float*)d_in[8];
    const float* wg    = (const float*)d_in[9];
    const float* wu    = (const float*)d_in[10];
    const float* wd    = (const float*)d_in[11];
    const float* lin_w = (const float*)d_in[12];
    const float* lin_b = (const float*)d_in[13];
    float* out = (float*)d_out;
    float* ws  = (float*)d_ws;

    // ---- workspace layout (f32 units; all 16B aligned) ----
    size_t o = 0;
    float*    X     = ws;                  o += (size_t)ROW_ * D_;            // f32
    ushort_t* QKVbf = (ushort_t*)(ws + o); o += (size_t)ROW_ * 1536 / 2;      // bf16
    ushort_t* Hb    = (ushort_t*)(ws + o); o += (size_t)ROW_ * D_ / 2;
    float*    OFY   = ws + o;              o += (size_t)ROW_ * NC_;           // region
    ushort_t* O     = (ushort_t*)OFY;                       // [ROW][512] bf16
    ushort_t* F     = (ushort_t*)(OFY + (size_t)ROW_ * D_ / 2);  // [ROW][2048] bf16
    float*    Yb    = OFY;                                  // [ROW][1282] f32 (after loop)
    float*    F2    = OFY;                                  // [2][ROW][641] f32 (after spec)
    ushort_t* wqkvT = (ushort_t*)(ws + o); o += (size_t)NL_ * 1536 * D_ / 2;
    ushort_t* woT   = (ushort_t*)(ws + o); o += (size_t)NL_ * D_ * D_ / 2;
    ushort_t* M2_h  = wqkvT;                                // [2][NHP2_][KH_] (after loop)
    ushort_t* wguT  = (ushort_t*)(ws + o); o += (size_t)NL_ * 4096 * D_ / 2;
    ushort_t* Ysp_h = wguT;                                 // [2][ROW][KH_] (after loop)
    ushort_t* wdT   = (ushort_t*)(ws + o); o += (size_t)NL_ * D_ * FF_ / 2;
    ushort_t* Hlo   = wdT;                                  // [ROW][512] (after loop)
    ushort_t* linTh = (ushort_t*)(ws + o); o += (size_t)NPADL * D_ / 2;
    ushort_t* linTl = (ushort_t*)(ws + o); o += (size_t)NPADL * D_ / 2;
    float*    Pp    = ws + o;              o += (size_t)2 * ROW_ * D_;        // split-K partials

    dim3 blk(256);

    k_embed<<<dim3((B_ * T_ * D_) / 256), blk, 0, stream>>>(codes, emb, X);

    // weight transpose-casts (batched over layers)
    k_castT<<<dim3(16, 16, NL_), blk, 0, stream>>>(wq, wqkvT,            nullptr, D_, D_, (long)D_*D_, (long)1536*D_);
    k_castT<<<dim3(16, 16, NL_), blk, 0, stream>>>(wk, wqkvT + 512*512,  nullptr, D_, D_, (long)D_*D_, (long)1536*D_);
    k_castT<<<dim3(16, 16, NL_), blk, 0, stream>>>(wv, wqkvT + 1024*512, nullptr, D_, D_, (long)D_*D_, (long)1536*D_);
    k_castT<<<dim3(16, 16, NL_), blk, 0, stream>>>(wo, woT,              nullptr, D_, D_, (long)D_*D_, (long)D_*D_);
    k_castT<<<dim3(64, 16, NL_), blk, 0, stream>>>(wg, wguT,             nullptr, D_, FF_, (long)D_*FF_, (long)4096*D_);
    k_castT<<<dim3(64, 16, NL_), blk, 0, stream>>>(wu, wguT + 2048*512,  nullptr, D_, FF_, (long)D_*FF_, (long)4096*D_);
    k_castT<<<dim3(16, 64, NL_), blk, 0, stream>>>(wd, wdT,              nullptr, FF_, D_, (long)FF_*D_, (long)D_*FF_);
    k_castT<<<dim3(NPADL/32, 16, 1), blk, 0, stream>>>(lin_w, linTh, linTl, D_, NC_, 0, 0);

    for (int l = 0; l < NL_; ++l) {
        // rmsnorm1: layers >0 fold in the previous wd's split-K partials
        k_rmsnorm<<<dim3(ROW_), blk, 0, stream>>>(
            X, (l == 0) ? nullptr : Pp, Pp + (size_t)ROW_ * D_, ln1 + l * D_, Hb, nullptr);
        gemm_wide<true><<<dim3(12, 48), blk, 0, stream>>>(
            Hb, wqkvT + (size_t)l * 1536 * D_, nullptr, QKVbf, D_, D_, 1536, 0, 0, 0);
        k_attn<<<dim3(B_ * H_ * (S_ / 32)), blk, 0, stream>>>(QKVbf, O);
        gemm_mfma<false,false,true,false><<<dim3(8, 48), blk, 0, stream>>>(
            O, nullptr, woT + (size_t)l * D_ * D_, nullptr,
            X, nullptr, X, nullptr, D_, D_, D_, 0, 0, 0);
        k_rmsnorm<<<dim3(ROW_), blk, 0, stream>>>(X, nullptr, nullptr, ln2 + l * D_, Hb, nullptr);
        gemm_swiglu<<<dim3(32, 48), blk, 0, stream>>>(
            Hb, wguT + (size_t)l * 4096 * D_, wguT + (size_t)l * 4096 * D_ + (size_t)2048 * D_, F, D_);
        // wd: split-K x2 -> partials Pp[0], Pp[1]; folded by next rmsnorm
        gemm_mfma<false,false,false,false><<<dim3(8, 48, 2), blk, 0, stream>>>(
            F, nullptr, wdT + (size_t)l * D_ * FF_, nullptr,
            nullptr, nullptr, Pp, nullptr, FF_ / 2, FF_, D_,
            (size_t)(FF_ / 2), (size_t)(FF_ / 2), (size_t)ROW_ * D_);
    }

    k_rmsnorm<<<dim3(ROW_), blk, 0, stream>>>(
        X, Pp, Pp + (size_t)ROW_ * D_, fln, Hb, Hlo);
    gemm_mfma<true,false,false,true><<<dim3(NPADL/64, 48), blk, 0, stream>>>(
        Hb, Hlo, linTh, linTl, nullptr, lin_b, Yb, nullptr, D_, D_, NC_, 0, 0, 0);
    {
        int total = 2 * ROW_ * KH_ + 2 * NHP2_ * KH_;
        k_specm<<<dim3((total + 255) / 256), blk, 0, stream>>>(Yb, Ysp_h, M2_h);
    }
    gemm_wide<false><<<dim3(NHP2_/128, 48, 2), blk, 0, stream>>>(
        Ysp_h, M2_h, F2, nullptr, KH_, KH_, NH_,
        (size_t)ROW_ * KH_, (size_t)NHP2_ * KH_, (size_t)ROW_ * NH_);
    k_overlap<<<dim3((B_ * OUTL_ + 255) / 256), blk, 0, stream>>>(F2, out);
}

// Round 10
// 560.664 us; speedup vs baseline: 1.1907x; 1.1669x over previous
//
#include <hip/hip_runtime.h>
#include <math.h>

// Problem constants (LFM2AudioDetokenizer)
#define B_    2
#define T_    256
#define S_    1536      // T*6
#define D_    512
#define H_    8
#define DH_   64
#define FF_   2048
#define V_    2048
#define NL_   4
#define NFFT_ 1280
#define HOP_  320
#define WIN_  1280
#define NBIN_ 641
#define NC_   1282
#define NPADL 1344      // 1282 padded to mult of 64 (final-linear col tiles)
#define PAD_  480
#define OUTL_ 491520    // (S-1)*HOP + WIN - 2*PAD
#define SWIN_ 30
#define ROW_  (B_ * S_) // 3072
// Half-spectrum ISTFT (cos/sin symmetry) dims
#define NH_   641       // output cols n = 0..640
#define KH_   704       // K = 641 padded to mult of 64
#define NHP2_ 768       // B rows padded to mult of 128 (wide tiles)

#define TWO_PI_OVER_N 0.004908738521234052f   // 2*pi/1280

typedef unsigned short ushort_t;
typedef __attribute__((ext_vector_type(8))) short short8;
typedef __attribute__((ext_vector_type(8))) unsigned short ushort8_t;
typedef __attribute__((ext_vector_type(4))) float f32x4;

__device__ __forceinline__ ushort_t f2bf(float x) {
    unsigned int u = __builtin_bit_cast(unsigned int, x);
    u = (u + 0x7fffu + ((u >> 16) & 1u)) >> 16;
    return (ushort_t)u;
}
__device__ __forceinline__ float bf2f(ushort_t h) {
    unsigned int u = ((unsigned int)h) << 16;
    return __builtin_bit_cast(float, u);
}

#define GLL16(gp, sp) \
    __builtin_amdgcn_global_load_lds((const __attribute__((address_space(1))) void*)(gp), \
                                     (__attribute__((address_space(3))) void*)(sp), 16, 0, 0)

// BK=64 swizzled LDS row: 128B = 8 x 16B slots; slot = (jg + (r>>1)) & 7.
__device__ __forceinline__ int fragoff(int r, int kg) {
    return r * 128 + (((kg + (r >> 1)) & 7) * 16);
}

// ---------------------------------------------------------------------------
__global__ __launch_bounds__(256) void k_embed(const int* __restrict__ codes,
                                               const float* __restrict__ emb,
                                               float* __restrict__ X)
{
    int idx = blockIdx.x * 256 + threadIdx.x;
    int d  = idx & (D_ - 1);
    int bt = idx >> 9;
    int t  = bt & (T_ - 1);
    int b  = bt >> 8;
    float s = 0.f;
#pragma unroll
    for (int cb = 0; cb < 8; ++cb) {
        int code = codes[(b * 8 + cb) * T_ + t];
        s += emb[(size_t)(cb * V_ + code) * D_ + d];
    }
    s *= 0.125f;
    float* xp = X + (size_t)(b * S_ + t * 6) * D_ + d;
#pragma unroll
    for (int r = 0; r < 6; ++r) xp[(size_t)r * D_] = s;
}

// ---------------------------------------------------------------------------
// RMSNorm over D=512 -> bf16. Optional: fuse partial-sum X += P0+P1 (split-K
// down-proj) with X write-back; optional lo output for split consumers.
__global__ __launch_bounds__(256) void k_rmsnorm(float* __restrict__ X,
                                                 const float* __restrict__ P0,
                                                 const float* __restrict__ P1,
                                                 const float* __restrict__ w,
                                                 ushort_t* __restrict__ Hh,
                                                 ushort_t* __restrict__ Hl)
{
    int row = blockIdx.x;
    int tid = threadIdx.x;
    float* x = X + (size_t)row * D_;
    float v0 = x[tid], v1 = x[tid + 256];
    if (P0) {
        size_t b = (size_t)row * D_;
        v0 += P0[b + tid] + P1[b + tid];
        v1 += P0[b + tid + 256] + P1[b + tid + 256];
        x[tid] = v0; x[tid + 256] = v1;
    }
    float ss = v0 * v0 + v1 * v1;
#pragma unroll
    for (int m = 1; m < 64; m <<= 1) ss += __shfl_xor(ss, m);
    __shared__ float red[4];
    if ((tid & 63) == 0) red[tid >> 6] = ss;
    __syncthreads();
    float tot = red[0] + red[1] + red[2] + red[3];
    float sc = rsqrtf(tot * (1.f / (float)D_) + 1e-5f);
    float y0 = v0 * sc * w[tid];
    float y1 = v1 * sc * w[tid + 256];
    ushort_t h0 = f2bf(y0), h1 = f2bf(y1);
    Hh[(size_t)row * D_ + tid]       = h0;
    Hh[(size_t)row * D_ + tid + 256] = h1;
    if (Hl) {
        Hl[(size_t)row * D_ + tid]       = f2bf(y0 - bf2f(h0));
        Hl[(size_t)row * D_ + tid + 256] = f2bf(y1 - bf2f(h1));
    }
}

// ---------------------------------------------------------------------------
// Transpose-cast f32 [K,N] -> bf16 [Npad,K] (rows >= N zero-filled).
__global__ __launch_bounds__(256) void k_castT(const float* __restrict__ src,
                                               ushort_t* __restrict__ dh,
                                               ushort_t* __restrict__ dl,
                                               int K, int N,
                                               long srcBatchStride, long dstBatchStride)
{
    src += (size_t)blockIdx.z * srcBatchStride;
    dh  += (size_t)blockIdx.z * dstBatchStride;
    if (dl) dl += (size_t)blockIdx.z * dstBatchStride;
    __shared__ float t[32][33];
    int n0 = blockIdx.x * 32, k0 = blockIdx.y * 32;
    int tx = threadIdx.x & 31, ty = threadIdx.x >> 5;   // 32 x 8
#pragma unroll
    for (int i = 0; i < 4; ++i) {
        int k = k0 + ty + 8 * i, n = n0 + tx;
        t[ty + 8 * i][tx] = (n < N) ? src[(size_t)k * N + n] : 0.f;
    }
    __syncthreads();
#pragma unroll
    for (int i = 0; i < 4; ++i) {
        int n = n0 + ty + 8 * i;
        float v = t[tx][ty + 8 * i];
        ushort_t h = f2bf(v);
        dh[(size_t)n * K + k0 + tx] = h;
        if (dl) dl[(size_t)n * K + k0 + tx] = f2bf(v - bf2f(h));
    }
}

// ---------------------------------------------------------------------------
// 64x64-tile MFMA GEMM, BK=64, XCD swizzle. SPLIT: bf16x2. Kloop may be a
// slice of Kstride (split-K via blockIdx.z + az/bz/cz pointer strides).
template<bool SPLIT, bool CBF16, bool HASRES, bool HASBIAS>
__global__ __launch_bounds__(256) void gemm_mfma(
    const ushort_t* __restrict__ Ah, const ushort_t* __restrict__ Al,
    const ushort_t* __restrict__ Bh, const ushort_t* __restrict__ Bl,
    const float* __restrict__ Res, const float* __restrict__ bias,
    float* __restrict__ Cf, ushort_t* __restrict__ Cb,
    int Kloop, int Kstride, int Nstore, size_t az, size_t bz, size_t cz)
{
    const size_t zo = blockIdx.z;
    Ah += zo * az; Bh += zo * bz;
    if (SPLIT) { Al += zo * az; Bl += zo * bz; }
    if (CBF16) Cb += zo * cz; else Cf += zo * cz;

    const int f  = blockIdx.y * gridDim.x + blockIdx.x;
    const int tx = f / gridDim.y;
    const int ty = f - tx * gridDim.y;

    __shared__ __align__(16) ushort_t lds[SPLIT ? 16384 : 8192];
    ushort_t* AsH = lds;            // 64 rows x 128B = 8KB
    ushort_t* BsH = lds + 4096;

    const int tid  = threadIdx.x;
    const int wave = tid >> 6, lane = tid & 63;
    const int row0 = ty * 64;
    const int col0 = tx * 64;
    const int wr = (wave >> 1) * 32, wc = (wave & 1) * 32;

    const int sr0 = tid >> 3, js = tid & 7;
    const int jg  = (js - (sr0 >> 1)) & 7;    // same for +32 rows (16 ≡ 0 mod 8)
    const size_t aSrc0 = (size_t)(row0 + sr0) * Kstride + jg * 8;
    const size_t aSrc1 = (size_t)(row0 + 32 + sr0) * Kstride + jg * 8;
    const size_t bSrc0 = (size_t)(col0 + sr0) * Kstride + jg * 8;
    const size_t bSrc1 = (size_t)(col0 + 32 + sr0) * Kstride + jg * 8;
    const int d0 = tid * 16, d1 = d0 + 4096;

    const int kg = lane >> 4;
    const int lr = lane & 15;
    const int offA0 = fragoff(wr + lr, kg);
    const int offA1 = fragoff(wr + 16 + lr, kg);
    const int offB0 = fragoff(wc + lr, kg);
    const int offB1 = fragoff(wc + 16 + lr, kg);

    f32x4 acc00 = {0.f,0.f,0.f,0.f}, acc01 = acc00, acc10 = acc00, acc11 = acc00;

    for (int k0 = 0; k0 < Kloop; k0 += 64) {
        GLL16(Ah + aSrc0 + k0, (char*)AsH + d0);
        GLL16(Ah + aSrc1 + k0, (char*)AsH + d1);
        GLL16(Bh + bSrc0 + k0, (char*)BsH + d0);
        GLL16(Bh + bSrc1 + k0, (char*)BsH + d1);
        if constexpr (SPLIT) {
            GLL16(Al + aSrc0 + k0, (char*)(lds + 8192)  + d0);
            GLL16(Al + aSrc1 + k0, (char*)(lds + 8192)  + d1);
            GLL16(Bl + bSrc0 + k0, (char*)(lds + 12288) + d0);
            GLL16(Bl + bSrc1 + k0, (char*)(lds + 12288) + d1);
        }
        __syncthreads();
#pragma unroll
        for (int h = 0; h < 2; ++h) {
            const int hx = h * 64;
            short8 a0 = *(const short8*)((const char*)AsH + (offA0 ^ hx));
            short8 a1 = *(const short8*)((const char*)AsH + (offA1 ^ hx));
            short8 b0 = *(const short8*)((const char*)BsH + (offB0 ^ hx));
            short8 b1 = *(const short8*)((const char*)BsH + (offB1 ^ hx));
            acc00 = __builtin_amdgcn_mfma_f32_16x16x32_bf16(a0, b0, acc00, 0, 0, 0);
            acc01 = __builtin_amdgcn_mfma_f32_16x16x32_bf16(a0, b1, acc01, 0, 0, 0);
            acc10 = __builtin_amdgcn_mfma_f32_16x16x32_bf16(a1, b0, acc10, 0, 0, 0);
            acc11 = __builtin_amdgcn_mfma_f32_16x16x32_bf16(a1, b1, acc11, 0, 0, 0);
            if constexpr (SPLIT) {
                short8 al0 = *(const short8*)((const char*)(lds + 8192)  + (offA0 ^ hx));
                short8 al1 = *(const short8*)((const char*)(lds + 8192)  + (offA1 ^ hx));
                short8 bl0 = *(const short8*)((const char*)(lds + 12288) + (offB0 ^ hx));
                short8 bl1 = *(const short8*)((const char*)(lds + 12288) + (offB1 ^ hx));
                acc00 = __builtin_amdgcn_mfma_f32_16x16x32_bf16(a0, bl0, acc00, 0, 0, 0);
                acc00 = __builtin_amdgcn_mfma_f32_16x16x32_bf16(al0, b0, acc00, 0, 0, 0);
                acc01 = __builtin_amdgcn_mfma_f32_16x16x32_bf16(a0, bl1, acc01, 0, 0, 0);
                acc01 = __builtin_amdgcn_mfma_f32_16x16x32_bf16(al0, b1, acc01, 0, 0, 0);
                acc10 = __builtin_amdgcn_mfma_f32_16x16x32_bf16(a1, bl0, acc10, 0, 0, 0);
                acc10 = __builtin_amdgcn_mfma_f32_16x16x32_bf16(al1, b0, acc10, 0, 0, 0);
                acc11 = __builtin_amdgcn_mfma_f32_16x16x32_bf16(a1, bl1, acc11, 0, 0, 0);
                acc11 = __builtin_amdgcn_mfma_f32_16x16x32_bf16(al1, b1, acc11, 0, 0, 0);
            }
        }
        __syncthreads();
    }

    const int crow = row0 + wr + (lane >> 4) * 4;
    const int ccol = col0 + wc + lr;
#pragma unroll
    for (int i = 0; i < 2; ++i) {
#pragma unroll
        for (int j = 0; j < 2; ++j) {
            const f32x4 a = (i == 0) ? (j == 0 ? acc00 : acc01) : (j == 0 ? acc10 : acc11);
            int c = ccol + j * 16;
            if (c >= Nstore) continue;
            float bi = HASBIAS ? bias[c] : 0.f;
#pragma unroll
            for (int r = 0; r < 4; ++r) {
                int rr = crow + i * 16 + r;
                float v = a[r] + bi;
                if (HASRES) v += Res[(size_t)rr * Nstore + c];
                if (CBF16) Cb[(size_t)rr * Nstore + c] = f2bf(v);
                else       Cf[(size_t)rr * Nstore + c] = v;
            }
        }
    }
}

// ---------------------------------------------------------------------------
// 64x128-tile MFMA GEMM (wide), BK=64. Each wave: 32 rows x 64 cols.
// Used for QKV (bf16 out) and ISTFT (f32 out, batched via z strides).
template<bool CBF16>
__global__ __launch_bounds__(256) void gemm_wide(
    const ushort_t* __restrict__ Ah, const ushort_t* __restrict__ Bh,
    float* __restrict__ Cf, ushort_t* __restrict__ Cb,
    int Kloop, int Kstride, int Nstore, size_t az, size_t bz, size_t cz)
{
    const size_t zo = blockIdx.z;
    Ah += zo * az; Bh += zo * bz;
    if (CBF16) Cb += zo * cz; else Cf += zo * cz;

    const int f  = blockIdx.y * gridDim.x + blockIdx.x;
    const int tx = f / gridDim.y;
    const int ty = f - tx * gridDim.y;

    __shared__ __align__(16) ushort_t lds[12288];   // A 8KB + B 16KB
    ushort_t* AsH = lds;
    ushort_t* BsH = lds + 4096;

    const int tid  = threadIdx.x;
    const int wave = tid >> 6, lane = tid & 63;
    const int row0 = ty * 64;
    const int col0 = tx * 128;
    const int wr  = (wave >> 1) * 32;
    const int wcc = (wave & 1) * 64;

    const int sr = tid >> 3, js = tid & 7;
    const int jg = (js - (sr >> 1)) & 7;    // invariant under +32 rows
    const int d0 = tid * 16;

    const int kg = lane >> 4;
    const int lr = lane & 15;
    const int offA0 = fragoff(wr + lr, kg);
    const int offA1 = fragoff(wr + 16 + lr, kg);
    int offB[4];
#pragma unroll
    for (int j = 0; j < 4; ++j) offB[j] = fragoff(wcc + 16 * j + lr, kg);

    f32x4 acc[2][4];
#pragma unroll
    for (int i = 0; i < 2; ++i)
#pragma unroll
        for (int j = 0; j < 4; ++j) acc[i][j] = (f32x4){0.f,0.f,0.f,0.f};

    for (int k0 = 0; k0 < Kloop; k0 += 64) {
#pragma unroll
        for (int p = 0; p < 2; ++p)
            GLL16(Ah + (size_t)(row0 + p * 32 + sr) * Kstride + jg * 8 + k0,
                  (char*)AsH + p * 4096 + d0);
#pragma unroll
        for (int p = 0; p < 4; ++p)
            GLL16(Bh + (size_t)(col0 + p * 32 + sr) * Kstride + jg * 8 + k0,
                  (char*)BsH + p * 4096 + d0);
        __syncthreads();
#pragma unroll
        for (int h = 0; h < 2; ++h) {
            const int hx = h * 64;
            short8 a0 = *(const short8*)((const char*)AsH + (offA0 ^ hx));
            short8 a1 = *(const short8*)((const char*)AsH + (offA1 ^ hx));
            short8 b[4];
#pragma unroll
            for (int j = 0; j < 4; ++j)
                b[j] = *(const short8*)((const char*)BsH + (offB[j] ^ hx));
#pragma unroll
            for (int j = 0; j < 4; ++j) {
                acc[0][j] = __builtin_amdgcn_mfma_f32_16x16x32_bf16(a0, b[j], acc[0][j], 0, 0, 0);
                acc[1][j] = __builtin_amdgcn_mfma_f32_16x16x32_bf16(a1, b[j], acc[1][j], 0, 0, 0);
            }
        }
        __syncthreads();
    }

    const int crow = row0 + wr + (lane >> 4) * 4;
    const int ccol = col0 + wcc + lr;
#pragma unroll
    for (int i = 0; i < 2; ++i) {
#pragma unroll
        for (int j = 0; j < 4; ++j) {
            int c = ccol + j * 16;
            if (c >= Nstore) continue;
#pragma unroll
            for (int r = 0; r < 4; ++r) {
                int rr = crow + i * 16 + r;
                if (CBF16) Cb[(size_t)rr * Nstore + c] = f2bf(acc[i][j][r]);
                else       Cf[(size_t)rr * Nstore + c] = acc[i][j][r];
            }
        }
    }
}

// ---------------------------------------------------------------------------
// 64x64-tile fused gate/up GEMM + SwiGLU -> bf16 F. BK=64, 24KB LDS,
// grid 32x48 = 1536 blocks (6/CU). [R6-proven shape]
__global__ __launch_bounds__(256) void gemm_swiglu(
    const ushort_t* __restrict__ Ah,
    const ushort_t* __restrict__ Bg, const ushort_t* __restrict__ Bu,
    ushort_t* __restrict__ F, int K)
{
    const int f  = blockIdx.y * gridDim.x + blockIdx.x;
    const int tx = f / gridDim.y;
    const int ty = f - tx * gridDim.y;

    __shared__ __align__(16) ushort_t lds[12288];   // A 8KB + Bg 8KB + Bu 8KB
    ushort_t* As  = lds;
    ushort_t* Bgs = lds + 4096;
    ushort_t* Bus = lds + 8192;

    const int tid  = threadIdx.x;
    const int wave = tid >> 6, lane = tid & 63;
    const int row0 = ty * 64;
    const int col0 = tx * 64;
    const int wr = (wave >> 1) * 32, wc = (wave & 1) * 32;

    const int sr0 = tid >> 3, js = tid & 7;
    const int jg  = (js - (sr0 >> 1)) & 7;
    const size_t aSrc0 = (size_t)(row0 + sr0) * K + jg * 8;
    const size_t aSrc1 = (size_t)(row0 + 32 + sr0) * K + jg * 8;
    const size_t bSrc0 = (size_t)(col0 + sr0) * K + jg * 8;
    const size_t bSrc1 = (size_t)(col0 + 32 + sr0) * K + jg * 8;
    const int d0 = tid * 16, d1 = d0 + 4096;

    const int kg = lane >> 4;
    const int lr = lane & 15;
    const int offA0 = fragoff(wr + lr, kg);
    const int offA1 = fragoff(wr + 16 + lr, kg);
    const int offB0 = fragoff(wc + lr, kg);
    const int offB1 = fragoff(wc + 16 + lr, kg);

    f32x4 g00 = {0.f,0.f,0.f,0.f}, g01 = g00, g10 = g00, g11 = g00;
    f32x4 u00 = g00, u01 = g00, u10 = g00, u11 = g00;

    for (int k0 = 0; k0 < K; k0 += 64) {
        GLL16(Ah + aSrc0 + k0, (char*)As  + d0);
        GLL16(Ah + aSrc1 + k0, (char*)As  + d1);
        GLL16(Bg + bSrc0 + k0, (char*)Bgs + d0);
        GLL16(Bg + bSrc1 + k0, (char*)Bgs + d1);
        GLL16(Bu + bSrc0 + k0, (char*)Bus + d0);
        GLL16(Bu + bSrc1 + k0, (char*)Bus + d1);
        __syncthreads();
#pragma unroll
        for (int h = 0; h < 2; ++h) {
            const int hx = h * 64;
            short8 a0  = *(const short8*)((const char*)As  + (offA0 ^ hx));
            short8 a1  = *(const short8*)((const char*)As  + (offA1 ^ hx));
            short8 bg0 = *(const short8*)((const char*)Bgs + (offB0 ^ hx));
            short8 bg1 = *(const short8*)((const char*)Bgs + (offB1 ^ hx));
            short8 bu0 = *(const short8*)((const char*)Bus + (offB0 ^ hx));
            short8 bu1 = *(const short8*)((const char*)Bus + (offB1 ^ hx));
            g00 = __builtin_amdgcn_mfma_f32_16x16x32_bf16(a0, bg0, g00, 0, 0, 0);
            g01 = __builtin_amdgcn_mfma_f32_16x16x32_bf16(a0, bg1, g01, 0, 0, 0);
            g10 = __builtin_amdgcn_mfma_f32_16x16x32_bf16(a1, bg0, g10, 0, 0, 0);
            g11 = __builtin_amdgcn_mfma_f32_16x16x32_bf16(a1, bg1, g11, 0, 0, 0);
            u00 = __builtin_amdgcn_mfma_f32_16x16x32_bf16(a0, bu0, u00, 0, 0, 0);
            u01 = __builtin_amdgcn_mfma_f32_16x16x32_bf16(a0, bu1, u01, 0, 0, 0);
            u10 = __builtin_amdgcn_mfma_f32_16x16x32_bf16(a1, bu0, u10, 0, 0, 0);
            u11 = __builtin_amdgcn_mfma_f32_16x16x32_bf16(a1, bu1, u11, 0, 0, 0);
        }
        __syncthreads();
    }

    const int crow = row0 + wr + (lane >> 4) * 4;
    const int ccol = col0 + wc + lr;
#pragma unroll
    for (int i = 0; i < 2; ++i) {
#pragma unroll
        for (int j = 0; j < 2; ++j) {
            const f32x4 g = (i == 0) ? (j == 0 ? g00 : g01) : (j == 0 ? g10 : g11);
            const f32x4 u = (i == 0) ? (j == 0 ? u00 : u01) : (j == 0 ? u10 : u11);
            int c = ccol + j * 16;
#pragma unroll
            for (int r = 0; r < 4; ++r) {
                int rr = crow + i * 16 + r;
                float gv = g[r];
                float v = (gv / (1.f + expf(-gv))) * u[r];
                F[(size_t)rr * FF_ + c] = f2bf(v);
            }
        }
    }
}

// ---------------------------------------------------------------------------
// Sliding-window causal attention, LDS-staged K/V window.
// Block = 32 consecutive queries of one (b,h); stages the 61-row K and V
// window (15.5KB) via global_load_lds once, then all score/PV reads hit LDS.
// Lane layout: 8 q's/wave, 8 lanes/q, 8 d-elems/lane.
__global__ __launch_bounds__(256) void k_attn(const ushort_t* __restrict__ QKV,
                                              ushort_t* __restrict__ O)
{
    __shared__ __align__(16) ushort_t Ks[64 * 64];   // 8KB (rows 0..60 used)
    __shared__ __align__(16) ushort_t Vs[64 * 64];   // 8KB

    const int tid  = threadIdx.x;
    const int wv   = tid >> 6;
    const int lane = tid & 63;
    const int qi = lane >> 3;          // q within wave
    const int dg = lane & 7;           // d-group (8 elems)
    const int nqb = S_ / 32;
    int blk  = blockIdx.x;             // over B*H*nqb
    int qblk = blk % nqb;
    int bh   = blk / nqb;
    int hh = bh & 7, bb = bh >> 3;
    const int r0 = qblk * 32 - (SWIN_ - 1);           // window start (may be <0)
    const ushort_t* base = QKV + (size_t)bb * S_ * 1536 + hh * 64;

    // stage K/V rows r0..r0+63 (clamped to 0) -> LDS. 2 passes x 32 rows.
    {
        const int sr = tid >> 3;               // 0..31 (8 rows per wave)
        const int sc = (tid & 7) * 8;          // 16B chunk
#pragma unroll
        for (int p = 0; p < 2; ++p) {
            int jc = r0 + p * 32 + sr; if (jc < 0) jc = 0;
            const ushort_t* src = base + (size_t)jc * 1536 + sc;
            GLL16(src + 512,  (char*)Ks + p * 4096 + tid * 16);
            GLL16(src + 1024, (char*)Vs + p * 4096 + tid * 16);
        }
    }

    const int qp = qblk * 32 + wv * 8 + qi;
    float q[8];
    {
        ushort8_t qv = *(const ushort8_t*)(base + (size_t)qp * 1536 + dg * 8);
#pragma unroll
        for (int d = 0; d < 8; ++d) q[d] = bf2f(qv[d]) * 0.125f;
    }
    __syncthreads();

    const int lrow0 = wv * 8 + qi;     // LDS row for jj=0
    float sc[SWIN_];
    float mx = -3.0e38f;
#pragma unroll
    for (int jj = 0; jj < SWIN_; ++jj) {
        int lr = lrow0 + jj;
        ushort8_t kv = *(const ushort8_t*)(Ks + lr * 64 + dg * 8);
        float p = 0.f;
#pragma unroll
        for (int d = 0; d < 8; ++d) p += q[d] * bf2f(kv[d]);
        p += __shfl_xor(p, 1);
        p += __shfl_xor(p, 2);
        p += __shfl_xor(p, 4);
        p = (r0 + lr >= 0) ? p : -1e30f;   // causal low-edge mask
        sc[jj] = p;
        mx = fmaxf(mx, p);
    }
    float den = 0.f;
#pragma unroll
    for (int jj = 0; jj < SWIN_; ++jj) { sc[jj] = __expf(sc[jj] - mx); den += sc[jj]; }
    float inv = 1.f / den;

    float acc[8] = {0.f,0.f,0.f,0.f,0.f,0.f,0.f,0.f};
#pragma unroll
    for (int jj = 0; jj < SWIN_; ++jj) {
        int lr = lrow0 + jj;
        ushort8_t vv = *(const ushort8_t*)(Vs + lr * 64 + dg * 8);
        float p = sc[jj];                  // 0 for masked (exp(-huge)=0)
#pragma unroll
        for (int d = 0; d < 8; ++d) acc[d] += p * bf2f(vv[d]);
    }
    ushort8_t ov;
#pragma unroll
    for (int d = 0; d < 8; ++d) ov[d] = f2bf(acc[d] * inv);
    *(ushort8_t*)(O + (size_t)(bb * S_ + qp) * 512 + hh * 64 + dg * 8) = ov;
}

// ---------------------------------------------------------------------------
// Fused: (1) Yb f32 [ROW][1282] -> bf16 half-spectra Ysp2[z][ROW][KH_]
//        (2) bf16 half synthesis matrices M2[z][NHP2_][KH_]
__global__ __launch_bounds__(256) void k_specm(const float* __restrict__ Y,
                                               ushort_t* __restrict__ Yh,
                                               ushort_t* __restrict__ Mh)
{
    int idx = blockIdx.x * 256 + threadIdx.x;
    const int P1 = 2 * ROW_ * KH_;
    if (idx < P1) {
        int k  = idx % KH_;
        int rz = idx / KH_;
        int row = rz % ROW_;
        int z   = rz / ROW_;
        float v = 0.f;
        if (k < NBIN_) {
            float la = Y[(size_t)row * NC_ + k];
            float an = Y[(size_t)row * NC_ + NBIN_ + k];
            float sn, cs;
            sincosf(an, &sn, &cs);
            v = expf(la) * (z ? sn : cs);
        }
        Yh[idx] = f2bf(v);
    } else {
        idx -= P1;
        if (idx >= 2 * NHP2_ * KH_) return;
        int k  = idx % KH_;
        int nz = idx / KH_;
        int n  = nz % NHP2_;
        int z  = nz / NHP2_;
        float val = 0.f;
        if (k < NBIN_ && n < NBIN_) {
            int kn = (k * n) % NFFT_;
            float ang = (float)kn * TWO_PI_OVER_N;
            float ck = (k == 0 || k == NBIN_ - 1) ? 1.f : 2.f;
            float win = 0.5f * (1.f - cosf((float)n * TWO_PI_OVER_N));
            float sn, cs;
            sincosf(ang, &sn, &cs);
            val = (z ? sn : cs) * ck * win * (1.f / (float)NFFT_);
        }
        Mh[idx] = f2bf(val);
    }
}

// ---------------------------------------------------------------------------
// Overlap-add gather + inline envelope from half-spectrum results:
// FR[n] = C[n]-S[n] (n<=640), C[1280-n]+S[1280-n] otherwise.
__global__ __launch_bounds__(256) void k_overlap(const float* __restrict__ F2,
                                                 float* __restrict__ out)
{
    int idx = blockIdx.x * 256 + threadIdx.x;
    if (idx >= B_ * OUTL_) return;
    int j = idx % OUTL_;
    int b = idx / OUTL_;
    int m = j + PAD_;
    int smax = m / HOP_;            if (smax > S_ - 1) smax = S_ - 1;
    int smin = (m - (WIN_ - HOP_)) / HOP_;
    if (smin < 0) smin = 0;
    const float* FS = F2 + (size_t)ROW_ * NH_;
    float acc = 0.f, env = 0.f;
    for (int s = smin; s <= smax; ++s) {
        int off = m - s * HOP_;
        size_t row = (size_t)(b * S_ + s) * NH_;
        float v;
        if (off < NBIN_) v = F2[row + off] - FS[row + off];
        else             v = F2[row + (NFFT_ - off)] + FS[row + (NFFT_ - off)];
        acc += v;
        float w = 0.5f * (1.f - cosf((float)off * TWO_PI_OVER_N));
        env += w * w;
    }
    out[idx] = acc / env;
}

// ---------------------------------------------------------------------------
extern "C" void kernel_launch(void* const* d_in, const int* in_sizes, int n_in,
                              void* d_out, int out_size, void* d_ws, size_t ws_size,
                              hipStream_t stream)
{
    (void)in_sizes; (void)n_in; (void)out_size; (void)ws_size;
    const int*   codes = (const int*)  d_in[0];
    const float* emb   = (const float*)d_in[1];
    const float* ln1   = (const float*)d_in[2];
    const float* ln2   = (const float*)d_in[3];
    const float* fln   = (const float*)d_in[4];
    const float* wq    = (const float*)d_in[5];
    const float* wk    = (const float*)d_in[6];
    const float* wv    = (const float*)d_in[7];
    const float* wo    = (const float*)d_in[8];
    const float* wg    = (const float*)d_in[9];
    const float* wu    = (const float*)d_in[10];
    const float* wd    = (const float*)d_in[11];
    const float* lin_w = (const float*)d_in[12];
    const float* lin_b = (const float*)d_in[13];
    float* out = (float*)d_out;
    float* ws  = (float*)d_ws;

    // ---- workspace layout (f32 units; all 16B aligned) ----
    size_t o = 0;
    float*    X     = ws;                  o += (size_t)ROW_ * D_;            // f32
    ushort_t* QKVbf = (ushort_t*)(ws + o); o += (size_t)ROW_ * 1536 / 2;      // bf16
    ushort_t* Hb    = (ushort_t*)(ws + o); o += (size_t)ROW_ * D_ / 2;
    float*    OFY   = ws + o;              o += (size_t)ROW_ * NC_;           // region
    ushort_t* O     = (ushort_t*)OFY;                       // [ROW][512] bf16
    ushort_t* F     = (ushort_t*)(OFY + (size_t)ROW_ * D_ / 2);  // [ROW][2048] bf16
    float*    Yb    = OFY;                                  // [ROW][1282] f32 (after loop)
    float*    F2    = OFY;                                  // [2][ROW][641] f32 (after spec)
    ushort_t* wqkvT = (ushort_t*)(ws + o); o += (size_t)NL_ * 1536 * D_ / 2;
    ushort_t* woT   = (ushort_t*)(ws + o); o += (size_t)NL_ * D_ * D_ / 2;
    ushort_t* M2_h  = wqkvT;                                // [2][NHP2_][KH_] (after loop)
    ushort_t* wguT  = (ushort_t*)(ws + o); o += (size_t)NL_ * 4096 * D_ / 2;
    ushort_t* Ysp_h = wguT;                                 // [2][ROW][KH_] (after loop)
    ushort_t* wdT   = (ushort_t*)(ws + o); o += (size_t)NL_ * D_ * FF_ / 2;
    ushort_t* Hlo   = wdT;                                  // [ROW][512] (after loop)
    ushort_t* linTh = (ushort_t*)(ws + o); o += (size_t)NPADL * D_ / 2;
    ushort_t* linTl = (ushort_t*)(ws + o); o += (size_t)NPADL * D_ / 2;
    float*    Pp    = ws + o;              o += (size_t)2 * ROW_ * D_;        // split-K partials

    dim3 blk(256);

    k_embed<<<dim3((B_ * T_ * D_) / 256), blk, 0, stream>>>(codes, emb, X);

    // weight transpose-casts (batched over layers)
    k_castT<<<dim3(16, 16, NL_), blk, 0, stream>>>(wq, wqkvT,            nullptr, D_, D_, (long)D_*D_, (long)1536*D_);
    k_castT<<<dim3(16, 16, NL_), blk, 0, stream>>>(wk, wqkvT + 512*512,  nullptr, D_, D_, (long)D_*D_, (long)1536*D_);
    k_castT<<<dim3(16, 16, NL_), blk, 0, stream>>>(wv, wqkvT + 1024*512, nullptr, D_, D_, (long)D_*D_, (long)1536*D_);
    k_castT<<<dim3(16, 16, NL_), blk, 0, stream>>>(wo, woT,              nullptr, D_, D_, (long)D_*D_, (long)D_*D_);
    k_castT<<<dim3(64, 16, NL_), blk, 0, stream>>>(wg, wguT,             nullptr, D_, FF_, (long)D_*FF_, (long)4096*D_);
    k_castT<<<dim3(64, 16, NL_), blk, 0, stream>>>(wu, wguT + 2048*512,  nullptr, D_, FF_, (long)D_*FF_, (long)4096*D_);
    k_castT<<<dim3(16, 64, NL_), blk, 0, stream>>>(wd, wdT,              nullptr, FF_, D_, (long)FF_*D_, (long)D_*FF_);
    k_castT<<<dim3(NPADL/32, 16, 1), blk, 0, stream>>>(lin_w, linTh, linTl, D_, NC_, 0, 0);

    for (int l = 0; l < NL_; ++l) {
        // rmsnorm1: layers >0 fold in the previous wd's split-K partials
        k_rmsnorm<<<dim3(ROW_), blk, 0, stream>>>(
            X, (l == 0) ? nullptr : Pp, Pp + (size_t)ROW_ * D_, ln1 + l * D_, Hb, nullptr);
        gemm_wide<true><<<dim3(12, 48), blk, 0, stream>>>(
            Hb, wqkvT + (size_t)l * 1536 * D_, nullptr, QKVbf, D_, D_, 1536, 0, 0, 0);
        k_attn<<<dim3(B_ * H_ * (S_ / 32)), blk, 0, stream>>>(QKVbf, O);
        gemm_mfma<false,false,true,false><<<dim3(8, 48), blk, 0, stream>>>(
            O, nullptr, woT + (size_t)l * D_ * D_, nullptr,
            X, nullptr, X, nullptr, D_, D_, D_, 0, 0, 0);
        k_rmsnorm<<<dim3(ROW_), blk, 0, stream>>>(X, nullptr, nullptr, ln2 + l * D_, Hb, nullptr);
        gemm_swiglu<<<dim3(32, 48), blk, 0, stream>>>(
            Hb, wguT + (size_t)l * 4096 * D_, wguT + (size_t)l * 4096 * D_ + (size_t)2048 * D_, F, D_);
        // wd: split-K x2 -> partials Pp[0], Pp[1]; folded by next rmsnorm
        gemm_mfma<false,false,false,false><<<dim3(8, 48, 2), blk, 0, stream>>>(
            F, nullptr, wdT + (size_t)l * D_ * FF_, nullptr,
            nullptr, nullptr, Pp, nullptr, FF_ / 2, FF_, D_,
            (size_t)(FF_ / 2), (size_t)(FF_ / 2), (size_t)ROW_ * D_);
    }

    k_rmsnorm<<<dim3(ROW_), blk, 0, stream>>>(
        X, Pp, Pp + (size_t)ROW_ * D_, fln, Hb, Hlo);
    gemm_mfma<true,false,false,true><<<dim3(NPADL/64, 48), blk, 0, stream>>>(
        Hb, Hlo, linTh, linTl, nullptr, lin_b, Yb, nullptr, D_, D_, NC_, 0, 0, 0);
    {
        int total = 2 * ROW_ * KH_ + 2 * NHP2_ * KH_;
        k_specm<<<dim3((total + 255) / 256), blk, 0, stream>>>(Yb, Ysp_h, M2_h);
    }
    gemm_wide<false><<<dim3(NHP2_/128, 48, 2), blk, 0, stream>>>(
        Ysp_h, M2_h, F2, nullptr, KH_, KH_, NH_,
        (size_t)ROW_ * KH_, (size_t)NHP2_ * KH_, (size_t)ROW_ * NH_);
    k_overlap<<<dim3((B_ * OUTL_ + 255) / 256), blk, 0, stream>>>(F2, out);
}